// Round 7
// baseline (537.873 us; speedup 1.0000x reference)
//
#include <hip/hip_runtime.h>
#include <hip/hip_bf16.h>

// GCN classifier: N=100000, E=1.6M, IN=64, HID=128, 64 graphs, 2 classes.
// Round 6: channel-sliced XCD-pinned gather aggregation. 128ch -> 8 slices of
// 16ch (32B), slice = blockIdx&7 -> per-XCD L2 working set 3.2MB (fits 4MB),
// turning the random row gather from L3-bound (~4TB/s) into L2 hits.

#define HID 128
#define NGRAPH 64
#define EPSN 1e-5f
#define BSHIFT 8            // 256 nodes per bucket
#define NBMAX 512

typedef unsigned int uint;
typedef unsigned short ushort;

static __device__ __forceinline__ ushort f2bf(float f) {  // round-nearest-even
  uint x = __float_as_uint(f);
  return (ushort)((x + 0x7FFFu + ((x >> 16) & 1u)) >> 16);
}
static __device__ __forceinline__ float bf_lo(uint u) { return __uint_as_float(u << 16); }
static __device__ __forceinline__ float bf_hi(uint u) {
  return __uint_as_float(u & 0xFFFF0000u);
}

// ---------------- per-graph segment boundaries (batch sorted) ----------------
__global__ __launch_bounds__(256) void graph_starts(const int* __restrict__ batch,
                                                    int* __restrict__ gstart, int N) {
  int i = blockIdx.x * 256 + threadIdx.x;
  if (i >= N) return;
  int g = batch[i];
  if (i == 0) {
    for (int q = 0; q <= g; ++q) gstart[q] = 0;
  } else {
    int gp = batch[i - 1];
    if (g != gp)
      for (int q = gp + 1; q <= g; ++q) gstart[q] = i;
  }
  if (i == N - 1)
    for (int q = g + 1; q <= NGRAPH; ++q) gstart[q] = N;
}

__global__ __launch_bounds__(64) void cnt_from_starts(const int* __restrict__ gstart,
                                                      float* __restrict__ cnt) {
  int g = threadIdx.x;
  if (g < NGRAPH) cnt[g] = (float)(gstart[g + 1] - gstart[g]);
}

// ---------------- bucketed counting sort: CSR build ----------------
__global__ __launch_bounds__(256) void bucket_count(const int* __restrict__ dst,
                                                    int* __restrict__ bcnt, int E, int NB) {
  __shared__ int h[NBMAX];
  for (int i = threadIdx.x; i < NB; i += 256) h[i] = 0;
  __syncthreads();
  int e0 = blockIdx.x * 4096;
#pragma unroll
  for (int k = 0; k < 16; ++k) {
    int e = e0 + k * 256 + threadIdx.x;
    if (e < E) atomicAdd(&h[dst[e] >> BSHIFT], 1);
  }
  __syncthreads();
  for (int i = threadIdx.x; i < NB; i += 256)
    if (h[i]) atomicAdd(&bcnt[i], h[i]);
}

__global__ __launch_bounds__(512) void bucket_scan(const int* __restrict__ bcnt,
                                                   int* __restrict__ bbase,
                                                   int* __restrict__ bcursor, int NB, int E) {
  __shared__ int sm[512];
  int t = threadIdx.x;
  int v = (t < NB) ? bcnt[t] : 0;
  sm[t] = v;
  __syncthreads();
  for (int off = 1; off < 512; off <<= 1) {
    int add = (t >= off) ? sm[t - off] : 0;
    __syncthreads();
    sm[t] += add;
    __syncthreads();
  }
  if (t < NB) {
    int excl = sm[t] - v;
    bbase[t] = excl;
    bcursor[t] = excl;
  }
  if (t == 0) bbase[NB] = E;
}

__global__ __launch_bounds__(256) void bin_edges(const int* __restrict__ src,
                                                 const int* __restrict__ dst,
                                                 int* __restrict__ bcursor,
                                                 int2* __restrict__ records, int E, int NB) {
  __shared__ int h[NBMAX];
  __shared__ int base[NBMAX];
  for (int i = threadIdx.x; i < NB; i += 256) h[i] = 0;
  __syncthreads();
  int e0 = blockIdx.x * 4096;
  int d[16], s[16];
#pragma unroll
  for (int k = 0; k < 16; ++k) {
    int e = e0 + k * 256 + threadIdx.x;
    if (e < E) {
      d[k] = dst[e];
      s[k] = src[e];
      atomicAdd(&h[d[k] >> BSHIFT], 1);
    }
  }
  __syncthreads();
  for (int i = threadIdx.x; i < NB; i += 256) {
    int c = h[i];
    if (c) base[i] = atomicAdd(&bcursor[i], c);
  }
  __syncthreads();
  for (int i = threadIdx.x; i < NB; i += 256) h[i] = 0;  // reuse as local cursor
  __syncthreads();
#pragma unroll
  for (int k = 0; k < 16; ++k) {
    int e = e0 + k * 256 + threadIdx.x;
    if (e < E) {
      int b = d[k] >> BSHIFT;
      int lp = atomicAdd(&h[b], 1);
      records[base[b] + lp] = make_int2(s[k], d[k]);
    }
  }
}

__global__ __launch_bounds__(256) void build_csr(const int2* __restrict__ records,
                                                 const int* __restrict__ bbase,
                                                 int* __restrict__ row_ptr,
                                                 float* __restrict__ dis,
                                                 int* __restrict__ esrc, int N, int E) {
  const int b = blockIdx.x;
  const int node0 = b << BSHIFT;
  const int nn = min(256, N - node0);
  const int beg = bbase[b];
  const int cnt = bbase[b + 1] - beg;
  const int t = threadIdx.x;
  __shared__ int lc[256], sc[256], lcur[256];
  lc[t] = 0;
  __syncthreads();
  for (int i = t; i < cnt; i += 256) atomicAdd(&lc[records[beg + i].y - node0], 1);
  __syncthreads();
  int myc = lc[t];
  sc[t] = myc;
  __syncthreads();
  for (int off = 1; off < 256; off <<= 1) {
    int add = (t >= off) ? sc[t - off] : 0;
    __syncthreads();
    sc[t] += add;
    __syncthreads();
  }
  int excl = sc[t] - myc;
  if (t < nn) {
    row_ptr[node0 + t] = beg + excl;
    dis[node0 + t] = rsqrtf((float)myc + 1.0f);  // +1 self-loop
  }
  lcur[t] = excl;
  __syncthreads();
  for (int i = t; i < cnt; i += 256) {
    int2 r = records[beg + i];
    int p = atomicAdd(&lcur[r.y - node0], 1);
    esrc[beg + p] = r.x;
  }
  if (b == 0 && t == 0) row_ptr[N] = E;
}

// ---------------- xs = bf16(x * dis[row]) ----------------
__global__ __launch_bounds__(256) void xscale_bf16(const float* __restrict__ X,
                                                   const float* __restrict__ dis,
                                                   ushort* __restrict__ XS, int n4) {
  int i4 = blockIdx.x * 256 + threadIdx.x;  // unit = float4
  if (i4 >= n4) return;
  int n = i4 >> 4;  // 16 float4 per 64-ch row
  float dn = dis[n];
  float4 v = ((const float4*)X)[i4];
  ushort4 u;
  u.x = f2bf(v.x * dn);
  u.y = f2bf(v.y * dn);
  u.z = f2bf(v.z * dn);
  u.w = f2bf(v.w * dn);
  ((ushort4*)XS)[i4] = u;
}

// ---------------- sliced aggregate, 64-ch input (4 slices x 16ch) ----------------
// blockIdx&7 -> XCD; real slice = v&3, half = v>>2 selects 32-node half.
// Wave: 8 nodes x 8 lanes; lane j holds channels (16*slice + 2j, +1).
__global__ __launch_bounds__(256) void aggregate64_sliced(const ushort* __restrict__ XS,
                                                          const int* __restrict__ row_ptr,
                                                          const int* __restrict__ esrc,
                                                          const float* __restrict__ dis,
                                                          float* __restrict__ out, int N) {
  const int v = blockIdx.x & 7;
  const int slice = v & 3;
  const int half = v >> 2;
  const int nb = blockIdx.x >> 3;
  const int w = threadIdx.x >> 6;
  const int grp = (threadIdx.x >> 3) & 7;
  const int j = threadIdx.x & 7;
  const int n = nb * 64 + half * 32 + w * 8 + grp;
  if (n >= N) return;
  const float dn = dis[n];
  const int beg = row_ptr[n];
  const int end = row_ptr[n + 1];
  const ushort* Xc = XS + slice * 16 + 2 * j;
  float ax = 0.f, ay = 0.f;
  int e = beg;
  for (; e + 1 < end; e += 2) {
    int s0 = esrc[e], s1 = esrc[e + 1];
    uint u0 = *(const uint*)(Xc + (size_t)s0 * 64);
    uint u1 = *(const uint*)(Xc + (size_t)s1 * 64);
    ax += bf_lo(u0) + bf_lo(u1);
    ay += bf_hi(u0) + bf_hi(u1);
  }
  if (e < end) {
    uint u0 = *(const uint*)(Xc + (size_t)esrc[e] * 64);
    ax += bf_lo(u0);
    ay += bf_hi(u0);
  }
  uint us = *(const uint*)(Xc + (size_t)n * 64);  // self (prescaled)
  ax += bf_lo(us);
  ay += bf_hi(us);
  float2 r;
  r.x = ax * dn;
  r.y = ay * dn;
  *(float2*)(out + (size_t)n * 64 + slice * 16 + 2 * j) = r;
}

// ---------------- sliced aggregate, 128-ch input (8 slices x 16ch) + bias ----------------
__global__ __launch_bounds__(256) void aggregate128_sliced(const ushort* __restrict__ H,
                                                           const int* __restrict__ row_ptr,
                                                           const int* __restrict__ esrc,
                                                           const float* __restrict__ dis,
                                                           const float* __restrict__ bias,
                                                           float* __restrict__ out, int N) {
  const int slice = blockIdx.x & 7;  // XCD-pinned channel slice
  const int nb = blockIdx.x >> 3;
  const int w = threadIdx.x >> 6;
  const int grp = (threadIdx.x >> 3) & 7;
  const int j = threadIdx.x & 7;
  const int n = nb * 32 + w * 8 + grp;
  if (n >= N) return;
  const float dn = dis[n];
  const int beg = row_ptr[n];
  const int end = row_ptr[n + 1];
  const int c = slice * 16 + 2 * j;
  const ushort* Hc = H + c;
  float ax = 0.f, ay = 0.f;
  int e = beg;
  for (; e + 1 < end; e += 2) {
    int s0 = esrc[e], s1 = esrc[e + 1];
    uint u0 = *(const uint*)(Hc + (size_t)s0 * HID);
    uint u1 = *(const uint*)(Hc + (size_t)s1 * HID);
    ax += bf_lo(u0) + bf_lo(u1);
    ay += bf_hi(u0) + bf_hi(u1);
  }
  if (e < end) {
    uint u0 = *(const uint*)(Hc + (size_t)esrc[e] * HID);
    ax += bf_lo(u0);
    ay += bf_hi(u0);
  }
  uint us = *(const uint*)(Hc + (size_t)n * HID);  // self (prescaled)
  ax += bf_lo(us);
  ay += bf_hi(us);
  float2 b = *(const float2*)(bias + c);
  float2 r;
  r.x = ax * dn + b.x;
  r.y = ay * dn + b.y;
  *(float2*)(out + (size_t)n * HID + c) = r;
}

// ---------------- GEMM tile: Y[N][128] = X[N][K] @ W[K][128] (+bias) ----------------
template <int K, bool FUSE_NORM, bool OUT_BF16, bool DIS_SCALE>
__global__ __launch_bounds__(256) void gemm_tile(const float* __restrict__ X,
                                                 const float* __restrict__ W,
                                                 const float* __restrict__ bias,
                                                 const int* __restrict__ batch,
                                                 const float* __restrict__ mean,
                                                 const float* __restrict__ inv,
                                                 const float* __restrict__ disv,
                                                 float* __restrict__ Yf,
                                                 ushort* __restrict__ Yh, int N) {
  __shared__ float Xs[64][68];
  __shared__ float Ws[64][HID];
  const int t = threadIdx.x;
  const int r0 = (t >> 4) * 4;
  const int c0 = (t & 15) * 8;
  const int row0 = blockIdx.x * 64;
  float acc[4][8] = {};
  for (int k0 = 0; k0 < K; k0 += 64) {
    for (int i = t; i < 64 * 32; i += 256) {
      int kk = i >> 5;
      int c4 = i & 31;
      ((float4*)&Ws[kk][0])[c4] = ((const float4*)(W + (size_t)(k0 + kk) * HID))[c4];
    }
    for (int i = t; i < 64 * 16; i += 256) {
      int r = i >> 4;
      int c4 = i & 15;
      int gr = row0 + r;
      float4 v = make_float4(0.f, 0.f, 0.f, 0.f);
      if (gr < N) {
        v = ((const float4*)(X + (size_t)gr * K + k0))[c4];
        if (FUSE_NORM) {
          int g = batch[gr];
          const float* mp = mean + g * HID + k0 + c4 * 4;
          const float* ip = inv + g * HID + k0 + c4 * 4;
          v.x = fmaxf((v.x - mp[0]) * ip[0], 0.f);
          v.y = fmaxf((v.y - mp[1]) * ip[1], 0.f);
          v.z = fmaxf((v.z - mp[2]) * ip[2], 0.f);
          v.w = fmaxf((v.w - mp[3]) * ip[3], 0.f);
        }
      }
      *(float4*)&Xs[r][c4 * 4] = v;
    }
    __syncthreads();
#pragma unroll 4
    for (int kk = 0; kk < 64; ++kk) {
      float4 w0 = *(const float4*)&Ws[kk][c0];
      float4 w1 = *(const float4*)&Ws[kk][c0 + 4];
      float xr[4];
#pragma unroll
      for (int i = 0; i < 4; ++i) xr[i] = Xs[r0 + i][kk];
#pragma unroll
      for (int i = 0; i < 4; ++i) {
        acc[i][0] += xr[i] * w0.x;
        acc[i][1] += xr[i] * w0.y;
        acc[i][2] += xr[i] * w0.z;
        acc[i][3] += xr[i] * w0.w;
        acc[i][4] += xr[i] * w1.x;
        acc[i][5] += xr[i] * w1.y;
        acc[i][6] += xr[i] * w1.z;
        acc[i][7] += xr[i] * w1.w;
      }
    }
    __syncthreads();
  }
  float bv[8];
#pragma unroll
  for (int j = 0; j < 8; ++j) bv[j] = bias ? bias[c0 + j] : 0.f;
#pragma unroll
  for (int i = 0; i < 4; ++i) {
    int gr = row0 + r0 + i;
    if (gr < N) {
      float ds = DIS_SCALE ? disv[gr] : 1.f;
      if (OUT_BF16) {
        uint4 u;
        u.x = (uint)f2bf((acc[i][0] + bv[0]) * ds) | ((uint)f2bf((acc[i][1] + bv[1]) * ds) << 16);
        u.y = (uint)f2bf((acc[i][2] + bv[2]) * ds) | ((uint)f2bf((acc[i][3] + bv[3]) * ds) << 16);
        u.z = (uint)f2bf((acc[i][4] + bv[4]) * ds) | ((uint)f2bf((acc[i][5] + bv[5]) * ds) << 16);
        u.w = (uint)f2bf((acc[i][6] + bv[6]) * ds) | ((uint)f2bf((acc[i][7] + bv[7]) * ds) << 16);
        *(uint4*)(Yh + (size_t)gr * HID + c0) = u;
      } else {
        float4 o0 = make_float4(acc[i][0] + bv[0], acc[i][1] + bv[1], acc[i][2] + bv[2],
                                acc[i][3] + bv[3]);
        float4 o1 = make_float4(acc[i][4] + bv[4], acc[i][5] + bv[5], acc[i][6] + bv[6],
                                acc[i][7] + bv[7]);
        *(float4*)(Yf + (size_t)gr * HID + c0) = o0;
        *(float4*)(Yf + (size_t)gr * HID + c0 + 4) = o1;
      }
    }
  }
}

// ---------------- per-graph sum/sumsq ----------------
__global__ __launch_bounds__(256) void stats_pass(const float* __restrict__ G,
                                                  const int* __restrict__ batch,
                                                  float* __restrict__ gsum,
                                                  float* __restrict__ gsq, int N) {
  const int c = threadIdx.x & 127;
  const int half = threadIdx.x >> 7;
  const int n0 = blockIdx.x * 64 + half * 32;
  const int n1 = min(n0 + 32, N);
  float s = 0.f, sq = 0.f;
  int cur = -1;
  for (int n = n0; n < n1; ++n) {
    int g = batch[n];
    if (g != cur) {
      if (cur >= 0) {
        atomicAdd(&gsum[cur * HID + c], s);
        atomicAdd(&gsq[cur * HID + c], sq);
      }
      cur = g;
      s = 0.f;
      sq = 0.f;
    }
    float val = G[(size_t)n * HID + c];
    s += val;
    sq += val * val;
  }
  if (cur >= 0) {
    atomicAdd(&gsum[cur * HID + c], s);
    atomicAdd(&gsq[cur * HID + c], sq);
  }
}

__global__ __launch_bounds__(256) void finalize_stats(const float* __restrict__ gsum,
                                                      const float* __restrict__ gsq,
                                                      const float* __restrict__ cnt,
                                                      float* __restrict__ mean,
                                                      float* __restrict__ inv) {
  int i = blockIdx.x * 256 + threadIdx.x;
  if (i >= NGRAPH * HID) return;
  int g = i >> 7;
  float c = fmaxf(cnt[g], 1.f);
  float m = gsum[i] / c;
  float v = gsq[i] / c - m * m;
  mean[i] = m;
  inv[i] = rsqrtf(v + EPSN);
}

__global__ __launch_bounds__(256) void norm_relu_pool(const float* __restrict__ G,
                                                      const int* __restrict__ batch,
                                                      const float* __restrict__ mean,
                                                      const float* __restrict__ inv,
                                                      float* __restrict__ pooled, int N) {
  const int c = threadIdx.x & 127;
  const int half = threadIdx.x >> 7;
  const int n0 = blockIdx.x * 64 + half * 32;
  const int n1 = min(n0 + 32, N);
  float s = 0.f;
  int cur = -1;
  for (int n = n0; n < n1; ++n) {
    int g = batch[n];
    if (g != cur) {
      if (cur >= 0) atomicAdd(&pooled[cur * HID + c], s);
      cur = g;
      s = 0.f;
    }
    float v = (G[(size_t)n * HID + c] - mean[g * HID + c]) * inv[g * HID + c];
    s += fmaxf(v, 0.f);
  }
  if (cur >= 0) atomicAdd(&pooled[cur * HID + c], s);
}

// ---------------- final head ----------------
__global__ __launch_bounds__(256) void final_head(const float* __restrict__ pooled_sum,
                                                  const float* __restrict__ cnt,
                                                  const float* __restrict__ gamma,
                                                  const float* __restrict__ beta,
                                                  const float* __restrict__ fcW,
                                                  const float* __restrict__ fcb,
                                                  float* __restrict__ out) {
  __shared__ float P[NGRAPH][HID];
  __shared__ float zs[HID], zb[HID];
  int t = threadIdx.x;
  for (int i = t; i < NGRAPH * HID; i += 256) {
    int g = i >> 7;
    P[g][i & 127] = pooled_sum[i] / fmaxf(cnt[g], 1.f);
  }
  __syncthreads();
  if (t < HID) {
    float m = 0.f;
    for (int g = 0; g < NGRAPH; ++g) m += P[g][t];
    m *= (1.f / NGRAPH);
    float v = 0.f;
    for (int g = 0; g < NGRAPH; ++g) {
      float d = P[g][t] - m;
      v += d * d;
    }
    v *= (1.f / NGRAPH);
    float sc = rsqrtf(v + EPSN) * gamma[t];
    zs[t] = sc;
    zb[t] = beta[t] - m * sc;
  }
  __syncthreads();
  if (t < NGRAPH * 2) {
    int g = t >> 1, k = t & 1;
    float acc = fcb[k];
    for (int c = 0; c < HID; ++c) {
      float z = P[g][c] * zs[c] + zb[c];
      acc += z * fcW[c * 2 + k];
    }
    out[t] = acc;
  }
}

extern "C" void kernel_launch(void* const* d_in, const int* in_sizes, int n_in,
                              void* d_out, int out_size, void* d_ws, size_t ws_size,
                              hipStream_t stream) {
  const float* x = (const float*)d_in[0];
  const int* ei = (const int*)d_in[1];     // int32
  const int* batch = (const int*)d_in[2];  // int32 (sorted)
  const float* W1 = (const float*)d_in[3];
  const float* b1 = (const float*)d_in[4];
  const float* W2 = (const float*)d_in[5];
  const float* b2 = (const float*)d_in[6];
  const float* gamma = (const float*)d_in[7];
  const float* beta = (const float*)d_in[8];
  const float* fcW = (const float*)d_in[9];
  const float* fcb = (const float*)d_in[10];
  float* out = (float*)d_out;

  const int N = in_sizes[2];
  const int E = in_sizes[1] / 2;
  const int* srcp = ei;
  const int* dstp = ei + E;
  const int NB = (N + 255) >> BSHIFT;  // buckets (<=512 for N<=131072)

  // workspace layout (floats)
  float* ws = (float*)d_ws;
  size_t off = 0;
  auto alloc = [&](size_t n) {
    float* p = ws + off;
    off += (n + 127) & ~(size_t)127;
    return p;
  };
  int* row_ptr = (int*)alloc(N + 1);
  int* esrc = (int*)alloc(E);
  float* recbuf = alloc((size_t)E * 2);  // int2 records; reused later as xs (bf16 Nx64)
  float* dis = alloc(N);
  float* y1 = alloc((size_t)N * 64);     // f32 Nx64; reused as h2s (bf16 Nx128)
  float* h1p = alloc((size_t)N * HID);   // f32: h1' then z
  int* bbase = (int*)alloc(NBMAX + 1);
  int* bcursor = (int*)alloc(NBMAX);
  int* gstart = (int*)alloc(NGRAPH + 1);
  float* zero0 = ws + off;               // zeroed region start
  int* bcnt = (int*)alloc(NBMAX);
  float* gsum1 = alloc(NGRAPH * HID);
  float* gsq1 = alloc(NGRAPH * HID);
  float* gsum2 = alloc(NGRAPH * HID);
  float* gsq2 = alloc(NGRAPH * HID);
  float* pooled = alloc(NGRAPH * HID);
  size_t zero_bytes = (size_t)((ws + off) - zero0) * sizeof(float);
  float* cnt = alloc(NGRAPH);
  float* mean1 = alloc(NGRAPH * HID);
  float* inv1 = alloc(NGRAPH * HID);
  float* mean2 = alloc(NGRAPH * HID);
  float* inv2 = alloc(NGRAPH * HID);

  int2* records = (int2*)recbuf;
  ushort* xs = (ushort*)recbuf;  // alias: records dead after build_csr
  ushort* h2s = (ushort*)y1;     // alias: y1 dead after gemm1

  const int nblkN = (N + 255) / 256;
  const int nblkE4k = (E + 4095) / 4096;

  hipMemsetAsync(zero0, 0, zero_bytes, stream);

  // graph segments + CSR build
  graph_starts<<<nblkN, 256, 0, stream>>>(batch, gstart, N);
  cnt_from_starts<<<1, 64, 0, stream>>>(gstart, cnt);
  bucket_count<<<nblkE4k, 256, 0, stream>>>(dstp, bcnt, E, NB);
  bucket_scan<<<1, 512, 0, stream>>>(bcnt, bbase, bcursor, NB, E);
  bin_edges<<<nblkE4k, 256, 0, stream>>>(srcp, dstp, bcursor, records, E, NB);
  build_csr<<<NB, 256, 0, stream>>>(records, bbase, row_ptr, dis, esrc, N, E);

  const int agg64Blocks = 8 * ((N + 63) / 64);   // 4 slices x 2 halves, 32 nodes/block
  const int agg128Blocks = 8 * ((N + 31) / 32);  // 8 slices, 32 nodes/block
  const int gemmBlocks = (N + 63) / 64;          // 64 rows per block

  // ---- layer 1: xs = bf16(x*dis); y1 = A-hat x ; h1' = y1 @ W1 + b1 ----
  xscale_bf16<<<(N * 16 + 255) / 256, 256, 0, stream>>>(x, dis, xs, N * 16);
  aggregate64_sliced<<<agg64Blocks, 256, 0, stream>>>(xs, row_ptr, esrc, dis, y1, N);
  gemm_tile<64, false, false, false><<<gemmBlocks, 256, 0, stream>>>(
      y1, W1, b1, nullptr, nullptr, nullptr, nullptr, h1p, nullptr, N);
  stats_pass<<<(N + 63) / 64, 256, 0, stream>>>(h1p, batch, gsum1, gsq1, N);
  finalize_stats<<<(NGRAPH * HID + 255) / 256, 256, 0, stream>>>(gsum1, gsq1, cnt, mean1, inv1);

  // ---- layer 2: h2s = bf16(relu(norm(h1')) @ W2 * dis) ; z = A-hat h2 + b2 ----
  gemm_tile<128, true, true, true><<<gemmBlocks, 256, 0, stream>>>(
      h1p, W2, nullptr, batch, mean1, inv1, dis, nullptr, h2s, N);
  aggregate128_sliced<<<agg128Blocks, 256, 0, stream>>>(h2s, row_ptr, esrc, dis, b2, h1p, N);
  stats_pass<<<(N + 63) / 64, 256, 0, stream>>>(h1p, batch, gsum2, gsq2, N);
  finalize_stats<<<(NGRAPH * HID + 255) / 256, 256, 0, stream>>>(gsum2, gsq2, cnt, mean2, inv2);
  norm_relu_pool<<<(N + 63) / 64, 256, 0, stream>>>(h1p, batch, mean2, inv2, pooled, N);

  // ---- head ----
  final_head<<<1, 256, 0, stream>>>(pooled, cnt, gamma, beta, fcW, fcb, out);
}

// Round 8
// 380.325 us; speedup vs baseline: 1.4142x; 1.4142x over previous
//
#include <hip/hip_runtime.h>
#include <hip/hip_bf16.h>

// GCN classifier: N=100000, E=1.6M, IN=64, HID=128, 64 graphs, 2 classes.
// Round 7: REVERT round-6 channel slicing (regression: 32B slice gathers
// overfetch 64B lines + 8x esrc re-read -> FETCH 191->657MB). Back to
// whole-row 256B coalesced gathers, now with 4-edge unroll for 2x more
// outstanding loads (round-5 profile: VALUBusy 30%, latency-bound).

#define HID 128
#define NGRAPH 64
#define EPSN 1e-5f
#define BSHIFT 8            // 256 nodes per bucket
#define NBMAX 512

typedef unsigned int uint;
typedef unsigned short ushort;

static __device__ __forceinline__ ushort f2bf(float f) {  // round-nearest-even
  uint x = __float_as_uint(f);
  return (ushort)((x + 0x7FFFu + ((x >> 16) & 1u)) >> 16);
}
static __device__ __forceinline__ float bf_lo(uint u) { return __uint_as_float(u << 16); }
static __device__ __forceinline__ float bf_hi(uint u) {
  return __uint_as_float(u & 0xFFFF0000u);
}

// ---------------- per-graph segment boundaries (batch sorted) ----------------
__global__ __launch_bounds__(256) void graph_starts(const int* __restrict__ batch,
                                                    int* __restrict__ gstart, int N) {
  int i = blockIdx.x * 256 + threadIdx.x;
  if (i >= N) return;
  int g = batch[i];
  if (i == 0) {
    for (int q = 0; q <= g; ++q) gstart[q] = 0;
  } else {
    int gp = batch[i - 1];
    if (g != gp)
      for (int q = gp + 1; q <= g; ++q) gstart[q] = i;
  }
  if (i == N - 1)
    for (int q = g + 1; q <= NGRAPH; ++q) gstart[q] = N;
}

__global__ __launch_bounds__(64) void cnt_from_starts(const int* __restrict__ gstart,
                                                      float* __restrict__ cnt) {
  int g = threadIdx.x;
  if (g < NGRAPH) cnt[g] = (float)(gstart[g + 1] - gstart[g]);
}

// ---------------- bucketed counting sort: CSR build ----------------
__global__ __launch_bounds__(256) void bucket_count(const int* __restrict__ dst,
                                                    int* __restrict__ bcnt, int E, int NB) {
  __shared__ int h[NBMAX];
  for (int i = threadIdx.x; i < NB; i += 256) h[i] = 0;
  __syncthreads();
  int e0 = blockIdx.x * 4096;
#pragma unroll
  for (int k = 0; k < 16; ++k) {
    int e = e0 + k * 256 + threadIdx.x;
    if (e < E) atomicAdd(&h[dst[e] >> BSHIFT], 1);
  }
  __syncthreads();
  for (int i = threadIdx.x; i < NB; i += 256)
    if (h[i]) atomicAdd(&bcnt[i], h[i]);
}

__global__ __launch_bounds__(512) void bucket_scan(const int* __restrict__ bcnt,
                                                   int* __restrict__ bbase,
                                                   int* __restrict__ bcursor, int NB, int E) {
  __shared__ int sm[512];
  int t = threadIdx.x;
  int v = (t < NB) ? bcnt[t] : 0;
  sm[t] = v;
  __syncthreads();
  for (int off = 1; off < 512; off <<= 1) {
    int add = (t >= off) ? sm[t - off] : 0;
    __syncthreads();
    sm[t] += add;
    __syncthreads();
  }
  if (t < NB) {
    int excl = sm[t] - v;
    bbase[t] = excl;
    bcursor[t] = excl;
  }
  if (t == 0) bbase[NB] = E;
}

__global__ __launch_bounds__(256) void bin_edges(const int* __restrict__ src,
                                                 const int* __restrict__ dst,
                                                 int* __restrict__ bcursor,
                                                 int2* __restrict__ records, int E, int NB) {
  __shared__ int h[NBMAX];
  __shared__ int base[NBMAX];
  for (int i = threadIdx.x; i < NB; i += 256) h[i] = 0;
  __syncthreads();
  int e0 = blockIdx.x * 4096;
  int d[16], s[16];
#pragma unroll
  for (int k = 0; k < 16; ++k) {
    int e = e0 + k * 256 + threadIdx.x;
    if (e < E) {
      d[k] = dst[e];
      s[k] = src[e];
      atomicAdd(&h[d[k] >> BSHIFT], 1);
    }
  }
  __syncthreads();
  for (int i = threadIdx.x; i < NB; i += 256) {
    int c = h[i];
    if (c) base[i] = atomicAdd(&bcursor[i], c);
  }
  __syncthreads();
  for (int i = threadIdx.x; i < NB; i += 256) h[i] = 0;  // reuse as local cursor
  __syncthreads();
#pragma unroll
  for (int k = 0; k < 16; ++k) {
    int e = e0 + k * 256 + threadIdx.x;
    if (e < E) {
      int b = d[k] >> BSHIFT;
      int lp = atomicAdd(&h[b], 1);
      records[base[b] + lp] = make_int2(s[k], d[k]);
    }
  }
}

__global__ __launch_bounds__(256) void build_csr(const int2* __restrict__ records,
                                                 const int* __restrict__ bbase,
                                                 int* __restrict__ row_ptr,
                                                 float* __restrict__ dis,
                                                 int* __restrict__ esrc, int N, int E) {
  const int b = blockIdx.x;
  const int node0 = b << BSHIFT;
  const int nn = min(256, N - node0);
  const int beg = bbase[b];
  const int cnt = bbase[b + 1] - beg;
  const int t = threadIdx.x;
  __shared__ int lc[256], sc[256], lcur[256];
  lc[t] = 0;
  __syncthreads();
  for (int i = t; i < cnt; i += 256) atomicAdd(&lc[records[beg + i].y - node0], 1);
  __syncthreads();
  int myc = lc[t];
  sc[t] = myc;
  __syncthreads();
  for (int off = 1; off < 256; off <<= 1) {
    int add = (t >= off) ? sc[t - off] : 0;
    __syncthreads();
    sc[t] += add;
    __syncthreads();
  }
  int excl = sc[t] - myc;
  if (t < nn) {
    row_ptr[node0 + t] = beg + excl;
    dis[node0 + t] = rsqrtf((float)myc + 1.0f);  // +1 self-loop
  }
  lcur[t] = excl;
  __syncthreads();
  for (int i = t; i < cnt; i += 256) {
    int2 r = records[beg + i];
    int p = atomicAdd(&lcur[r.y - node0], 1);
    esrc[beg + p] = r.x;
  }
  if (b == 0 && t == 0) row_ptr[N] = E;
}

// ---------------- xs = bf16(x * dis[row]) ----------------
__global__ __launch_bounds__(256) void xscale_bf16(const float* __restrict__ X,
                                                   const float* __restrict__ dis,
                                                   ushort* __restrict__ XS, int n4) {
  int i4 = blockIdx.x * 256 + threadIdx.x;  // unit = float4
  if (i4 >= n4) return;
  int n = i4 >> 4;  // 16 float4 per 64-ch row
  float dn = dis[n];
  float4 v = ((const float4*)X)[i4];
  ushort4 u;
  u.x = f2bf(v.x * dn);
  u.y = f2bf(v.y * dn);
  u.z = f2bf(v.z * dn);
  u.w = f2bf(v.w * dn);
  ((ushort4*)XS)[i4] = u;
}

// ---------------- aggregate 64-ch bf16 (prescaled), 4-edge unroll ----------------
// one wave per node; lane holds 1 channel (bf16), row = 128B coalesced.
__global__ __launch_bounds__(256) void aggregate64_bf16(const ushort* __restrict__ XS,
                                                        const int* __restrict__ row_ptr,
                                                        const int* __restrict__ esrc,
                                                        const float* __restrict__ dis,
                                                        float* __restrict__ out, int N) {
  int wid = (int)((blockIdx.x * 256 + threadIdx.x) >> 6);
  if (wid >= N) return;
  const int lane = threadIdx.x & 63;
  const float dn = dis[wid];
  const int beg = row_ptr[wid];
  const int end = row_ptr[wid + 1];
  const ushort* Xl = XS + lane;
  float a0 = 0.f, a1 = 0.f;
  int e = beg;
  for (; e + 3 < end; e += 4) {
    int s0 = esrc[e], s1 = esrc[e + 1], s2 = esrc[e + 2], s3 = esrc[e + 3];
    ushort v0 = Xl[(size_t)s0 * 64];
    ushort v1 = Xl[(size_t)s1 * 64];
    ushort v2 = Xl[(size_t)s2 * 64];
    ushort v3 = Xl[(size_t)s3 * 64];
    a0 += __uint_as_float((uint)v0 << 16) + __uint_as_float((uint)v1 << 16);
    a1 += __uint_as_float((uint)v2 << 16) + __uint_as_float((uint)v3 << 16);
  }
  for (; e < end; ++e) a0 += __uint_as_float((uint)Xl[(size_t)esrc[e] * 64] << 16);
  a0 += a1 + __uint_as_float((uint)Xl[(size_t)wid * 64] << 16);  // + self (prescaled)
  out[(size_t)wid * 64 + lane] = a0 * dn;
}

// ---------------- aggregate 128-ch bf16 (prescaled) + bias, 4-edge unroll ----------------
// one wave per node; lane holds 2 channels (uint), row = 256B coalesced.
__global__ __launch_bounds__(256) void aggregate128_bf16(const ushort* __restrict__ H,
                                                         const int* __restrict__ row_ptr,
                                                         const int* __restrict__ esrc,
                                                         const float* __restrict__ dis,
                                                         const float* __restrict__ bias,
                                                         float* __restrict__ out, int N) {
  int wid = (int)((blockIdx.x * 256 + threadIdx.x) >> 6);
  if (wid >= N) return;
  const int lane = threadIdx.x & 63;
  const float dn = dis[wid];
  const int beg = row_ptr[wid];
  const int end = row_ptr[wid + 1];
  const ushort* Hl = H + 2 * lane;
  float ax = 0.f, ay = 0.f, bx = 0.f, by = 0.f;
  int e = beg;
  for (; e + 3 < end; e += 4) {
    int s0 = esrc[e], s1 = esrc[e + 1], s2 = esrc[e + 2], s3 = esrc[e + 3];
    uint u0 = *(const uint*)(Hl + (size_t)s0 * HID);
    uint u1 = *(const uint*)(Hl + (size_t)s1 * HID);
    uint u2 = *(const uint*)(Hl + (size_t)s2 * HID);
    uint u3 = *(const uint*)(Hl + (size_t)s3 * HID);
    ax += bf_lo(u0) + bf_lo(u1);
    ay += bf_hi(u0) + bf_hi(u1);
    bx += bf_lo(u2) + bf_lo(u3);
    by += bf_hi(u2) + bf_hi(u3);
  }
  for (; e < end; ++e) {
    uint u0 = *(const uint*)(Hl + (size_t)esrc[e] * HID);
    ax += bf_lo(u0);
    ay += bf_hi(u0);
  }
  uint us = *(const uint*)(Hl + (size_t)wid * HID);  // self (prescaled)
  ax += bx + bf_lo(us);
  ay += by + bf_hi(us);
  float2 b = ((const float2*)bias)[lane];
  float2 r;
  r.x = ax * dn + b.x;
  r.y = ay * dn + b.y;
  ((float2*)(out + (size_t)wid * HID))[lane] = r;
}

// ---------------- GEMM tile: Y[N][128] = X[N][K] @ W[K][128] (+bias) ----------------
template <int K, bool FUSE_NORM, bool OUT_BF16, bool DIS_SCALE>
__global__ __launch_bounds__(256) void gemm_tile(const float* __restrict__ X,
                                                 const float* __restrict__ W,
                                                 const float* __restrict__ bias,
                                                 const int* __restrict__ batch,
                                                 const float* __restrict__ mean,
                                                 const float* __restrict__ inv,
                                                 const float* __restrict__ disv,
                                                 float* __restrict__ Yf,
                                                 ushort* __restrict__ Yh, int N) {
  __shared__ float Xs[64][68];
  __shared__ float Ws[64][HID];
  const int t = threadIdx.x;
  const int r0 = (t >> 4) * 4;
  const int c0 = (t & 15) * 8;
  const int row0 = blockIdx.x * 64;
  float acc[4][8] = {};
  for (int k0 = 0; k0 < K; k0 += 64) {
    for (int i = t; i < 64 * 32; i += 256) {
      int kk = i >> 5;
      int c4 = i & 31;
      ((float4*)&Ws[kk][0])[c4] = ((const float4*)(W + (size_t)(k0 + kk) * HID))[c4];
    }
    for (int i = t; i < 64 * 16; i += 256) {
      int r = i >> 4;
      int c4 = i & 15;
      int gr = row0 + r;
      float4 v = make_float4(0.f, 0.f, 0.f, 0.f);
      if (gr < N) {
        v = ((const float4*)(X + (size_t)gr * K + k0))[c4];
        if (FUSE_NORM) {
          int g = batch[gr];
          const float* mp = mean + g * HID + k0 + c4 * 4;
          const float* ip = inv + g * HID + k0 + c4 * 4;
          v.x = fmaxf((v.x - mp[0]) * ip[0], 0.f);
          v.y = fmaxf((v.y - mp[1]) * ip[1], 0.f);
          v.z = fmaxf((v.z - mp[2]) * ip[2], 0.f);
          v.w = fmaxf((v.w - mp[3]) * ip[3], 0.f);
        }
      }
      *(float4*)&Xs[r][c4 * 4] = v;
    }
    __syncthreads();
#pragma unroll 4
    for (int kk = 0; kk < 64; ++kk) {
      float4 w0 = *(const float4*)&Ws[kk][c0];
      float4 w1 = *(const float4*)&Ws[kk][c0 + 4];
      float xr[4];
#pragma unroll
      for (int i = 0; i < 4; ++i) xr[i] = Xs[r0 + i][kk];
#pragma unroll
      for (int i = 0; i < 4; ++i) {
        acc[i][0] += xr[i] * w0.x;
        acc[i][1] += xr[i] * w0.y;
        acc[i][2] += xr[i] * w0.z;
        acc[i][3] += xr[i] * w0.w;
        acc[i][4] += xr[i] * w1.x;
        acc[i][5] += xr[i] * w1.y;
        acc[i][6] += xr[i] * w1.z;
        acc[i][7] += xr[i] * w1.w;
      }
    }
    __syncthreads();
  }
  float bv[8];
#pragma unroll
  for (int j = 0; j < 8; ++j) bv[j] = bias ? bias[c0 + j] : 0.f;
#pragma unroll
  for (int i = 0; i < 4; ++i) {
    int gr = row0 + r0 + i;
    if (gr < N) {
      float ds = DIS_SCALE ? disv[gr] : 1.f;
      if (OUT_BF16) {
        uint4 u;
        u.x = (uint)f2bf((acc[i][0] + bv[0]) * ds) | ((uint)f2bf((acc[i][1] + bv[1]) * ds) << 16);
        u.y = (uint)f2bf((acc[i][2] + bv[2]) * ds) | ((uint)f2bf((acc[i][3] + bv[3]) * ds) << 16);
        u.z = (uint)f2bf((acc[i][4] + bv[4]) * ds) | ((uint)f2bf((acc[i][5] + bv[5]) * ds) << 16);
        u.w = (uint)f2bf((acc[i][6] + bv[6]) * ds) | ((uint)f2bf((acc[i][7] + bv[7]) * ds) << 16);
        *(uint4*)(Yh + (size_t)gr * HID + c0) = u;
      } else {
        float4 o0 = make_float4(acc[i][0] + bv[0], acc[i][1] + bv[1], acc[i][2] + bv[2],
                                acc[i][3] + bv[3]);
        float4 o1 = make_float4(acc[i][4] + bv[4], acc[i][5] + bv[5], acc[i][6] + bv[6],
                                acc[i][7] + bv[7]);
        *(float4*)(Yf + (size_t)gr * HID + c0) = o0;
        *(float4*)(Yf + (size_t)gr * HID + c0 + 4) = o1;
      }
    }
  }
}

// ---------------- per-graph sum/sumsq ----------------
__global__ __launch_bounds__(256) void stats_pass(const float* __restrict__ G,
                                                  const int* __restrict__ batch,
                                                  float* __restrict__ gsum,
                                                  float* __restrict__ gsq, int N) {
  const int c = threadIdx.x & 127;
  const int half = threadIdx.x >> 7;
  const int n0 = blockIdx.x * 64 + half * 32;
  const int n1 = min(n0 + 32, N);
  float s = 0.f, sq = 0.f;
  int cur = -1;
  for (int n = n0; n < n1; ++n) {
    int g = batch[n];
    if (g != cur) {
      if (cur >= 0) {
        atomicAdd(&gsum[cur * HID + c], s);
        atomicAdd(&gsq[cur * HID + c], sq);
      }
      cur = g;
      s = 0.f;
      sq = 0.f;
    }
    float val = G[(size_t)n * HID + c];
    s += val;
    sq += val * val;
  }
  if (cur >= 0) {
    atomicAdd(&gsum[cur * HID + c], s);
    atomicAdd(&gsq[cur * HID + c], sq);
  }
}

__global__ __launch_bounds__(256) void finalize_stats(const float* __restrict__ gsum,
                                                      const float* __restrict__ gsq,
                                                      const float* __restrict__ cnt,
                                                      float* __restrict__ mean,
                                                      float* __restrict__ inv) {
  int i = blockIdx.x * 256 + threadIdx.x;
  if (i >= NGRAPH * HID) return;
  int g = i >> 7;
  float c = fmaxf(cnt[g], 1.f);
  float m = gsum[i] / c;
  float v = gsq[i] / c - m * m;
  mean[i] = m;
  inv[i] = rsqrtf(v + EPSN);
}

__global__ __launch_bounds__(256) void norm_relu_pool(const float* __restrict__ G,
                                                      const int* __restrict__ batch,
                                                      const float* __restrict__ mean,
                                                      const float* __restrict__ inv,
                                                      float* __restrict__ pooled, int N) {
  const int c = threadIdx.x & 127;
  const int half = threadIdx.x >> 7;
  const int n0 = blockIdx.x * 64 + half * 32;
  const int n1 = min(n0 + 32, N);
  float s = 0.f;
  int cur = -1;
  for (int n = n0; n < n1; ++n) {
    int g = batch[n];
    if (g != cur) {
      if (cur >= 0) atomicAdd(&pooled[cur * HID + c], s);
      cur = g;
      s = 0.f;
    }
    float v = (G[(size_t)n * HID + c] - mean[g * HID + c]) * inv[g * HID + c];
    s += fmaxf(v, 0.f);
  }
  if (cur >= 0) atomicAdd(&pooled[cur * HID + c], s);
}

// ---------------- final head ----------------
__global__ __launch_bounds__(256) void final_head(const float* __restrict__ pooled_sum,
                                                  const float* __restrict__ cnt,
                                                  const float* __restrict__ gamma,
                                                  const float* __restrict__ beta,
                                                  const float* __restrict__ fcW,
                                                  const float* __restrict__ fcb,
                                                  float* __restrict__ out) {
  __shared__ float P[NGRAPH][HID];
  __shared__ float zs[HID], zb[HID];
  int t = threadIdx.x;
  for (int i = t; i < NGRAPH * HID; i += 256) {
    int g = i >> 7;
    P[g][i & 127] = pooled_sum[i] / fmaxf(cnt[g], 1.f);
  }
  __syncthreads();
  if (t < HID) {
    float m = 0.f;
    for (int g = 0; g < NGRAPH; ++g) m += P[g][t];
    m *= (1.f / NGRAPH);
    float v = 0.f;
    for (int g = 0; g < NGRAPH; ++g) {
      float d = P[g][t] - m;
      v += d * d;
    }
    v *= (1.f / NGRAPH);
    float sc = rsqrtf(v + EPSN) * gamma[t];
    zs[t] = sc;
    zb[t] = beta[t] - m * sc;
  }
  __syncthreads();
  if (t < NGRAPH * 2) {
    int g = t >> 1, k = t & 1;
    float acc = fcb[k];
    for (int c = 0; c < HID; ++c) {
      float z = P[g][c] * zs[c] + zb[c];
      acc += z * fcW[c * 2 + k];
    }
    out[t] = acc;
  }
}

extern "C" void kernel_launch(void* const* d_in, const int* in_sizes, int n_in,
                              void* d_out, int out_size, void* d_ws, size_t ws_size,
                              hipStream_t stream) {
  const float* x = (const float*)d_in[0];
  const int* ei = (const int*)d_in[1];     // int32
  const int* batch = (const int*)d_in[2];  // int32 (sorted)
  const float* W1 = (const float*)d_in[3];
  const float* b1 = (const float*)d_in[4];
  const float* W2 = (const float*)d_in[5];
  const float* b2 = (const float*)d_in[6];
  const float* gamma = (const float*)d_in[7];
  const float* beta = (const float*)d_in[8];
  const float* fcW = (const float*)d_in[9];
  const float* fcb = (const float*)d_in[10];
  float* out = (float*)d_out;

  const int N = in_sizes[2];
  const int E = in_sizes[1] / 2;
  const int* srcp = ei;
  const int* dstp = ei + E;
  const int NB = (N + 255) >> BSHIFT;  // buckets (<=512 for N<=131072)

  // workspace layout (floats)
  float* ws = (float*)d_ws;
  size_t off = 0;
  auto alloc = [&](size_t n) {
    float* p = ws + off;
    off += (n + 127) & ~(size_t)127;
    return p;
  };
  int* row_ptr = (int*)alloc(N + 1);
  int* esrc = (int*)alloc(E);
  float* recbuf = alloc((size_t)E * 2);  // int2 records; reused later as xs (bf16 Nx64)
  float* dis = alloc(N);
  float* y1 = alloc((size_t)N * 64);     // f32 Nx64; reused as h2s (bf16 Nx128)
  float* h1p = alloc((size_t)N * HID);   // f32: h1' then z
  int* bbase = (int*)alloc(NBMAX + 1);
  int* bcursor = (int*)alloc(NBMAX);
  int* gstart = (int*)alloc(NGRAPH + 1);
  float* zero0 = ws + off;               // zeroed region start
  int* bcnt = (int*)alloc(NBMAX);
  float* gsum1 = alloc(NGRAPH * HID);
  float* gsq1 = alloc(NGRAPH * HID);
  float* gsum2 = alloc(NGRAPH * HID);
  float* gsq2 = alloc(NGRAPH * HID);
  float* pooled = alloc(NGRAPH * HID);
  size_t zero_bytes = (size_t)((ws + off) - zero0) * sizeof(float);
  float* cnt = alloc(NGRAPH);
  float* mean1 = alloc(NGRAPH * HID);
  float* inv1 = alloc(NGRAPH * HID);
  float* mean2 = alloc(NGRAPH * HID);
  float* inv2 = alloc(NGRAPH * HID);

  int2* records = (int2*)recbuf;
  ushort* xs = (ushort*)recbuf;  // alias: records dead after build_csr
  ushort* h2s = (ushort*)y1;     // alias: y1 dead after gemm1

  const int nblkN = (N + 255) / 256;
  const int nblkE4k = (E + 4095) / 4096;

  hipMemsetAsync(zero0, 0, zero_bytes, stream);

  // graph segments + CSR build
  graph_starts<<<nblkN, 256, 0, stream>>>(batch, gstart, N);
  cnt_from_starts<<<1, 64, 0, stream>>>(gstart, cnt);
  bucket_count<<<nblkE4k, 256, 0, stream>>>(dstp, bcnt, E, NB);
  bucket_scan<<<1, 512, 0, stream>>>(bcnt, bbase, bcursor, NB, E);
  bin_edges<<<nblkE4k, 256, 0, stream>>>(srcp, dstp, bcursor, records, E, NB);
  build_csr<<<NB, 256, 0, stream>>>(records, bbase, row_ptr, dis, esrc, N, E);

  const int aggBlocks = (N + 3) / 4;     // one wave per node
  const int gemmBlocks = (N + 63) / 64;  // 64 rows per block

  // ---- layer 1: xs = bf16(x*dis); y1 = A-hat x ; h1' = y1 @ W1 + b1 ----
  xscale_bf16<<<(N * 16 + 255) / 256, 256, 0, stream>>>(x, dis, xs, N * 16);
  aggregate64_bf16<<<aggBlocks, 256, 0, stream>>>(xs, row_ptr, esrc, dis, y1, N);
  gemm_tile<64, false, false, false><<<gemmBlocks, 256, 0, stream>>>(
      y1, W1, b1, nullptr, nullptr, nullptr, nullptr, h1p, nullptr, N);
  stats_pass<<<(N + 63) / 64, 256, 0, stream>>>(h1p, batch, gsum1, gsq1, N);
  finalize_stats<<<(NGRAPH * HID + 255) / 256, 256, 0, stream>>>(gsum1, gsq1, cnt, mean1, inv1);

  // ---- layer 2: h2s = bf16(relu(norm(h1')) @ W2 * dis) ; z = A-hat h2 + b2 ----
  gemm_tile<128, true, true, true><<<gemmBlocks, 256, 0, stream>>>(
      h1p, W2, nullptr, batch, mean1, inv1, dis, nullptr, h2s, N);
  aggregate128_bf16<<<aggBlocks, 256, 0, stream>>>(h2s, row_ptr, esrc, dis, b2, h1p, N);
  stats_pass<<<(N + 63) / 64, 256, 0, stream>>>(h1p, batch, gsum2, gsq2, N);
  finalize_stats<<<(NGRAPH * HID + 255) / 256, 256, 0, stream>>>(gsum2, gsq2, cnt, mean2, inv2);
  norm_relu_pool<<<(N + 63) / 64, 256, 0, stream>>>(h1p, batch, mean2, inv2, pooled, N);

  // ---- head ----
  final_head<<<1, 256, 0, stream>>>(pooled, cnt, gamma, beta, fcW, fcb, out);
}

// Round 9
// 364.918 us; speedup vs baseline: 1.4740x; 1.0422x over previous
//
#include <hip/hip_runtime.h>
#include <hip/hip_bf16.h>

// GCN classifier: N=100000, E=1.6M, IN=64, HID=128, 64 graphs, 2 classes.
// Round 8: (a) half-wave paired gathers (2 rows / 512B per instruction),
// (b) bf16 for ALL N*128 intermediates (h1, z, y1) -> ~128MB less traffic,
// (c) packed 32-bit CSR records (src<<8 | dst&255).

#define HID 128
#define NGRAPH 64
#define EPSN 1e-5f
#define BSHIFT 8            // 256 nodes per bucket
#define NBMAX 512

typedef unsigned int uint;
typedef unsigned short ushort;

static __device__ __forceinline__ ushort f2bf(float f) {  // round-nearest-even
  uint x = __float_as_uint(f);
  return (ushort)((x + 0x7FFFu + ((x >> 16) & 1u)) >> 16);
}
static __device__ __forceinline__ float bf_lo(uint u) { return __uint_as_float(u << 16); }
static __device__ __forceinline__ float bf_hi(uint u) {
  return __uint_as_float(u & 0xFFFF0000u);
}

// ---------------- per-graph segment boundaries (batch sorted) ----------------
__global__ __launch_bounds__(256) void graph_starts(const int* __restrict__ batch,
                                                    int* __restrict__ gstart, int N) {
  int i = blockIdx.x * 256 + threadIdx.x;
  if (i >= N) return;
  int g = batch[i];
  if (i == 0) {
    for (int q = 0; q <= g; ++q) gstart[q] = 0;
  } else {
    int gp = batch[i - 1];
    if (g != gp)
      for (int q = gp + 1; q <= g; ++q) gstart[q] = i;
  }
  if (i == N - 1)
    for (int q = g + 1; q <= NGRAPH; ++q) gstart[q] = N;
}

__global__ __launch_bounds__(64) void cnt_from_starts(const int* __restrict__ gstart,
                                                      float* __restrict__ cnt) {
  int g = threadIdx.x;
  if (g < NGRAPH) cnt[g] = (float)(gstart[g + 1] - gstart[g]);
}

// ---------------- bucketed counting sort: CSR build ----------------
__global__ __launch_bounds__(256) void bucket_count(const int* __restrict__ dst,
                                                    int* __restrict__ bcnt, int E, int NB) {
  __shared__ int h[NBMAX];
  for (int i = threadIdx.x; i < NB; i += 256) h[i] = 0;
  __syncthreads();
  int e0 = blockIdx.x * 4096;
#pragma unroll
  for (int k = 0; k < 16; ++k) {
    int e = e0 + k * 256 + threadIdx.x;
    if (e < E) atomicAdd(&h[dst[e] >> BSHIFT], 1);
  }
  __syncthreads();
  for (int i = threadIdx.x; i < NB; i += 256)
    if (h[i]) atomicAdd(&bcnt[i], h[i]);
}

__global__ __launch_bounds__(512) void bucket_scan(const int* __restrict__ bcnt,
                                                   int* __restrict__ bbase,
                                                   int* __restrict__ bcursor, int NB, int E) {
  __shared__ int sm[512];
  int t = threadIdx.x;
  int v = (t < NB) ? bcnt[t] : 0;
  sm[t] = v;
  __syncthreads();
  for (int off = 1; off < 512; off <<= 1) {
    int add = (t >= off) ? sm[t - off] : 0;
    __syncthreads();
    sm[t] += add;
    __syncthreads();
  }
  if (t < NB) {
    int excl = sm[t] - v;
    bbase[t] = excl;
    bcursor[t] = excl;
  }
  if (t == 0) bbase[NB] = E;
}

// packed record: (src << 8) | (dst & 255)   [src < 2^24]
__global__ __launch_bounds__(256) void bin_edges(const int* __restrict__ src,
                                                 const int* __restrict__ dst,
                                                 int* __restrict__ bcursor,
                                                 uint* __restrict__ records, int E, int NB) {
  __shared__ int h[NBMAX];
  __shared__ int base[NBMAX];
  for (int i = threadIdx.x; i < NB; i += 256) h[i] = 0;
  __syncthreads();
  int e0 = blockIdx.x * 4096;
  int d[16], s[16];
#pragma unroll
  for (int k = 0; k < 16; ++k) {
    int e = e0 + k * 256 + threadIdx.x;
    if (e < E) {
      d[k] = dst[e];
      s[k] = src[e];
      atomicAdd(&h[d[k] >> BSHIFT], 1);
    }
  }
  __syncthreads();
  for (int i = threadIdx.x; i < NB; i += 256) {
    int c = h[i];
    if (c) base[i] = atomicAdd(&bcursor[i], c);
  }
  __syncthreads();
  for (int i = threadIdx.x; i < NB; i += 256) h[i] = 0;  // reuse as local cursor
  __syncthreads();
#pragma unroll
  for (int k = 0; k < 16; ++k) {
    int e = e0 + k * 256 + threadIdx.x;
    if (e < E) {
      int b = d[k] >> BSHIFT;
      int lp = atomicAdd(&h[b], 1);
      records[base[b] + lp] = ((uint)s[k] << 8) | (uint)(d[k] & 255);
    }
  }
}

__global__ __launch_bounds__(256) void build_csr(const uint* __restrict__ records,
                                                 const int* __restrict__ bbase,
                                                 int* __restrict__ row_ptr,
                                                 float* __restrict__ dis,
                                                 int* __restrict__ esrc, int N, int E) {
  const int b = blockIdx.x;
  const int node0 = b << BSHIFT;
  const int nn = min(256, N - node0);
  const int beg = bbase[b];
  const int cnt = bbase[b + 1] - beg;
  const int t = threadIdx.x;
  __shared__ int lc[256], sc[256], lcur[256];
  lc[t] = 0;
  __syncthreads();
  for (int i = t; i < cnt; i += 256) atomicAdd(&lc[records[beg + i] & 255u], 1);
  __syncthreads();
  int myc = lc[t];
  sc[t] = myc;
  __syncthreads();
  for (int off = 1; off < 256; off <<= 1) {
    int add = (t >= off) ? sc[t - off] : 0;
    __syncthreads();
    sc[t] += add;
    __syncthreads();
  }
  int excl = sc[t] - myc;
  if (t < nn) {
    row_ptr[node0 + t] = beg + excl;
    dis[node0 + t] = rsqrtf((float)myc + 1.0f);  // +1 self-loop
  }
  lcur[t] = excl;
  __syncthreads();
  for (int i = t; i < cnt; i += 256) {
    uint r = records[beg + i];
    int p = atomicAdd(&lcur[r & 255u], 1);
    esrc[beg + p] = (int)(r >> 8);
  }
  if (b == 0 && t == 0) row_ptr[N] = E;
}

// ---------------- xs = bf16(x * dis[row]) ----------------
__global__ __launch_bounds__(256) void xscale_bf16(const float* __restrict__ X,
                                                   const float* __restrict__ dis,
                                                   ushort* __restrict__ XS, int n4) {
  int i4 = blockIdx.x * 256 + threadIdx.x;  // unit = float4
  if (i4 >= n4) return;
  int n = i4 >> 4;  // 16 float4 per 64-ch row
  float dn = dis[n];
  float4 v = ((const float4*)X)[i4];
  ushort4 u;
  u.x = f2bf(v.x * dn);
  u.y = f2bf(v.y * dn);
  u.z = f2bf(v.z * dn);
  u.w = f2bf(v.w * dn);
  ((ushort4*)XS)[i4] = u;
}

// ---------------- aggregate 64-ch bf16, half-wave paired edges ----------------
// one wave per node; halves take even/odd edges; lane = uint (2 ch), 2 rows/instr.
__global__ __launch_bounds__(256) void aggregate64_bf16(const ushort* __restrict__ XS,
                                                        const int* __restrict__ row_ptr,
                                                        const int* __restrict__ esrc,
                                                        const float* __restrict__ dis,
                                                        ushort* __restrict__ out, int N) {
  int wid = (int)((blockIdx.x * 256 + threadIdx.x) >> 6);
  if (wid >= N) return;
  const int lane = threadIdx.x & 63;
  const int h = lane >> 5;   // edge parity
  const int c2 = lane & 31;  // uint index (channels 2*c2, 2*c2+1)
  const float dn = dis[wid];
  const int beg = row_ptr[wid];
  const int end = row_ptr[wid + 1];
  const uint* X32 = (const uint*)XS;
  float ax = 0.f, ay = 0.f, bx = 0.f, by = 0.f;
  int e = beg;
  for (; e + 3 < end; e += 4) {  // 4 edges/iter: 2 per half
    int s0 = esrc[e + h];
    int s1 = esrc[e + 2 + h];
    uint u0 = X32[(size_t)s0 * 32 + c2];
    uint u1 = X32[(size_t)s1 * 32 + c2];
    ax += bf_lo(u0);
    ay += bf_hi(u0);
    bx += bf_lo(u1);
    by += bf_hi(u1);
  }
  for (; e < end; e += 2) {
    if (e + h < end) {
      uint u0 = X32[(size_t)esrc[e + h] * 32 + c2];
      ax += bf_lo(u0);
      ay += bf_hi(u0);
    }
  }
  ax += bx;
  ay += by;
  ax += __shfl_xor(ax, 32, 64);
  ay += __shfl_xor(ay, 32, 64);
  if (h == 0) {
    uint us = X32[(size_t)wid * 32 + c2];  // self (prescaled)
    ax = (ax + bf_lo(us)) * dn;
    ay = (ay + bf_hi(us)) * dn;
    ((uint*)out)[(size_t)wid * 32 + c2] = (uint)f2bf(ax) | ((uint)f2bf(ay) << 16);
  }
}

// ---------------- aggregate 128-ch bf16 + bias, half-wave paired edges ----------------
// one wave per node; lane = uint2 (4 ch), 2 rows / 512B per instruction.
__global__ __launch_bounds__(256) void aggregate128_bf16(const ushort* __restrict__ H,
                                                         const int* __restrict__ row_ptr,
                                                         const int* __restrict__ esrc,
                                                         const float* __restrict__ dis,
                                                         const float* __restrict__ bias,
                                                         ushort* __restrict__ outz, int N) {
  int wid = (int)((blockIdx.x * 256 + threadIdx.x) >> 6);
  if (wid >= N) return;
  const int lane = threadIdx.x & 63;
  const int h = lane >> 5;   // edge parity
  const int c4 = lane & 31;  // uint2 index (channels 4*c4 .. 4*c4+3)
  const float dn = dis[wid];
  const int beg = row_ptr[wid];
  const int end = row_ptr[wid + 1];
  const uint2* H2 = (const uint2*)H;
  float a0 = 0.f, a1 = 0.f, a2 = 0.f, a3 = 0.f;
  float b0 = 0.f, b1v = 0.f, b2v = 0.f, b3 = 0.f;
  int e = beg;
  for (; e + 3 < end; e += 4) {  // 4 edges/iter: 2 per half
    int s0 = esrc[e + h];
    int s1 = esrc[e + 2 + h];
    uint2 u0 = H2[(size_t)s0 * 32 + c4];
    uint2 u1 = H2[(size_t)s1 * 32 + c4];
    a0 += bf_lo(u0.x);
    a1 += bf_hi(u0.x);
    a2 += bf_lo(u0.y);
    a3 += bf_hi(u0.y);
    b0 += bf_lo(u1.x);
    b1v += bf_hi(u1.x);
    b2v += bf_lo(u1.y);
    b3 += bf_hi(u1.y);
  }
  for (; e < end; e += 2) {
    if (e + h < end) {
      uint2 u0 = H2[(size_t)esrc[e + h] * 32 + c4];
      a0 += bf_lo(u0.x);
      a1 += bf_hi(u0.x);
      a2 += bf_lo(u0.y);
      a3 += bf_hi(u0.y);
    }
  }
  a0 += b0;
  a1 += b1v;
  a2 += b2v;
  a3 += b3;
  a0 += __shfl_xor(a0, 32, 64);
  a1 += __shfl_xor(a1, 32, 64);
  a2 += __shfl_xor(a2, 32, 64);
  a3 += __shfl_xor(a3, 32, 64);
  if (h == 0) {
    uint2 us = H2[(size_t)wid * 32 + c4];  // self (prescaled)
    float4 b = ((const float4*)bias)[c4];
    float r0 = (a0 + bf_lo(us.x)) * dn + b.x;
    float r1 = (a1 + bf_hi(us.x)) * dn + b.y;
    float r2 = (a2 + bf_lo(us.y)) * dn + b.z;
    float r3 = (a3 + bf_hi(us.y)) * dn + b.w;
    uint2 o;
    o.x = (uint)f2bf(r0) | ((uint)f2bf(r1) << 16);
    o.y = (uint)f2bf(r2) | ((uint)f2bf(r3) << 16);
    ((uint2*)outz)[(size_t)wid * 32 + c4] = o;
  }
}

// ---------------- GEMM tile: Y[N][128] = bf16X[N][K] @ W[K][128] (+bias) -> bf16 ----------------
// 64 rows x 128 ch per block; thread = 4 rows x 8 contiguous ch.
template <int K, bool FUSE_NORM, bool DIS_SCALE>
__global__ __launch_bounds__(256) void gemm_tile(const ushort* __restrict__ X,
                                                 const float* __restrict__ W,
                                                 const float* __restrict__ bias,
                                                 const int* __restrict__ batch,
                                                 const float* __restrict__ mean,
                                                 const float* __restrict__ inv,
                                                 const float* __restrict__ disv,
                                                 ushort* __restrict__ Y, int N) {
  __shared__ float Xs[64][68];
  __shared__ float Ws[64][HID];
  const int t = threadIdx.x;
  const int r0 = (t >> 4) * 4;
  const int c0 = (t & 15) * 8;
  const int row0 = blockIdx.x * 64;
  float acc[4][8] = {};
  for (int k0 = 0; k0 < K; k0 += 64) {
    for (int i = t; i < 64 * 32; i += 256) {  // W: 64x128 in float4 units
      int kk = i >> 5;
      int c4 = i & 31;
      ((float4*)&Ws[kk][0])[c4] = ((const float4*)(W + (size_t)(k0 + kk) * HID))[c4];
    }
    for (int i = t; i < 64 * 8; i += 256) {  // X: 64 rows x 64 k, 16B (8 bf16) units
      int r = i >> 3;
      int u = i & 7;
      int gr = row0 + r;
      float f[8];
      if (gr < N) {
        uint4 v = *(const uint4*)(X + (size_t)gr * K + k0 + u * 8);
        f[0] = bf_lo(v.x);
        f[1] = bf_hi(v.x);
        f[2] = bf_lo(v.y);
        f[3] = bf_hi(v.y);
        f[4] = bf_lo(v.z);
        f[5] = bf_hi(v.z);
        f[6] = bf_lo(v.w);
        f[7] = bf_hi(v.w);
        if (FUSE_NORM) {
          int g = batch[gr];
          const float* mp = mean + g * HID + k0 + u * 8;
          const float* ip = inv + g * HID + k0 + u * 8;
#pragma unroll
          for (int j = 0; j < 8; ++j) f[j] = fmaxf((f[j] - mp[j]) * ip[j], 0.f);
        }
      } else {
#pragma unroll
        for (int j = 0; j < 8; ++j) f[j] = 0.f;
      }
#pragma unroll
      for (int j = 0; j < 8; ++j) Xs[r][u * 8 + j] = f[j];
    }
    __syncthreads();
#pragma unroll 4
    for (int kk = 0; kk < 64; ++kk) {
      float4 w0 = *(const float4*)&Ws[kk][c0];
      float4 w1 = *(const float4*)&Ws[kk][c0 + 4];
      float xr[4];
#pragma unroll
      for (int i = 0; i < 4; ++i) xr[i] = Xs[r0 + i][kk];
#pragma unroll
      for (int i = 0; i < 4; ++i) {
        acc[i][0] += xr[i] * w0.x;
        acc[i][1] += xr[i] * w0.y;
        acc[i][2] += xr[i] * w0.z;
        acc[i][3] += xr[i] * w0.w;
        acc[i][4] += xr[i] * w1.x;
        acc[i][5] += xr[i] * w1.y;
        acc[i][6] += xr[i] * w1.z;
        acc[i][7] += xr[i] * w1.w;
      }
    }
    __syncthreads();
  }
  float bv[8];
#pragma unroll
  for (int j = 0; j < 8; ++j) bv[j] = bias ? bias[c0 + j] : 0.f;
#pragma unroll
  for (int i = 0; i < 4; ++i) {
    int gr = row0 + r0 + i;
    if (gr < N) {
      float ds = DIS_SCALE ? disv[gr] : 1.f;
      uint4 u;
      u.x = (uint)f2bf((acc[i][0] + bv[0]) * ds) | ((uint)f2bf((acc[i][1] + bv[1]) * ds) << 16);
      u.y = (uint)f2bf((acc[i][2] + bv[2]) * ds) | ((uint)f2bf((acc[i][3] + bv[3]) * ds) << 16);
      u.z = (uint)f2bf((acc[i][4] + bv[4]) * ds) | ((uint)f2bf((acc[i][5] + bv[5]) * ds) << 16);
      u.w = (uint)f2bf((acc[i][6] + bv[6]) * ds) | ((uint)f2bf((acc[i][7] + bv[7]) * ds) << 16);
      *(uint4*)(Y + (size_t)gr * HID + c0) = u;
    }
  }
}

// ---------------- per-graph sum/sumsq (bf16 input) ----------------
__global__ __launch_bounds__(256) void stats_pass(const ushort* __restrict__ G,
                                                  const int* __restrict__ batch,
                                                  float* __restrict__ gsum,
                                                  float* __restrict__ gsq, int N) {
  const int c = threadIdx.x & 127;
  const int half = threadIdx.x >> 7;
  const int n0 = blockIdx.x * 64 + half * 32;
  const int n1 = min(n0 + 32, N);
  float s = 0.f, sq = 0.f;
  int cur = -1;
  for (int n = n0; n < n1; ++n) {
    int g = batch[n];
    if (g != cur) {
      if (cur >= 0) {
        atomicAdd(&gsum[cur * HID + c], s);
        atomicAdd(&gsq[cur * HID + c], sq);
      }
      cur = g;
      s = 0.f;
      sq = 0.f;
    }
    float val = __uint_as_float((uint)G[(size_t)n * HID + c] << 16);
    s += val;
    sq += val * val;
  }
  if (cur >= 0) {
    atomicAdd(&gsum[cur * HID + c], s);
    atomicAdd(&gsq[cur * HID + c], sq);
  }
}

__global__ __launch_bounds__(256) void finalize_stats(const float* __restrict__ gsum,
                                                      const float* __restrict__ gsq,
                                                      const float* __restrict__ cnt,
                                                      float* __restrict__ mean,
                                                      float* __restrict__ inv) {
  int i = blockIdx.x * 256 + threadIdx.x;
  if (i >= NGRAPH * HID) return;
  int g = i >> 7;
  float c = fmaxf(cnt[g], 1.f);
  float m = gsum[i] / c;
  float v = gsq[i] / c - m * m;
  mean[i] = m;
  inv[i] = rsqrtf(v + EPSN);
}

__global__ __launch_bounds__(256) void norm_relu_pool(const ushort* __restrict__ G,
                                                      const int* __restrict__ batch,
                                                      const float* __restrict__ mean,
                                                      const float* __restrict__ inv,
                                                      float* __restrict__ pooled, int N) {
  const int c = threadIdx.x & 127;
  const int half = threadIdx.x >> 7;
  const int n0 = blockIdx.x * 64 + half * 32;
  const int n1 = min(n0 + 32, N);
  float s = 0.f;
  int cur = -1;
  for (int n = n0; n < n1; ++n) {
    int g = batch[n];
    if (g != cur) {
      if (cur >= 0) atomicAdd(&pooled[cur * HID + c], s);
      cur = g;
      s = 0.f;
    }
    float val = __uint_as_float((uint)G[(size_t)n * HID + c] << 16);
    float v = (val - mean[g * HID + c]) * inv[g * HID + c];
    s += fmaxf(v, 0.f);
  }
  if (cur >= 0) atomicAdd(&pooled[cur * HID + c], s);
}

// ---------------- final head ----------------
__global__ __launch_bounds__(256) void final_head(const float* __restrict__ pooled_sum,
                                                  const float* __restrict__ cnt,
                                                  const float* __restrict__ gamma,
                                                  const float* __restrict__ beta,
                                                  const float* __restrict__ fcW,
                                                  const float* __restrict__ fcb,
                                                  float* __restrict__ out) {
  __shared__ float P[NGRAPH][HID];
  __shared__ float zs[HID], zb[HID];
  int t = threadIdx.x;
  for (int i = t; i < NGRAPH * HID; i += 256) {
    int g = i >> 7;
    P[g][i & 127] = pooled_sum[i] / fmaxf(cnt[g], 1.f);
  }
  __syncthreads();
  if (t < HID) {
    float m = 0.f;
    for (int g = 0; g < NGRAPH; ++g) m += P[g][t];
    m *= (1.f / NGRAPH);
    float v = 0.f;
    for (int g = 0; g < NGRAPH; ++g) {
      float d = P[g][t] - m;
      v += d * d;
    }
    v *= (1.f / NGRAPH);
    float sc = rsqrtf(v + EPSN) * gamma[t];
    zs[t] = sc;
    zb[t] = beta[t] - m * sc;
  }
  __syncthreads();
  if (t < NGRAPH * 2) {
    int g = t >> 1, k = t & 1;
    float acc = fcb[k];
    for (int c = 0; c < HID; ++c) {
      float z = P[g][c] * zs[c] + zb[c];
      acc += z * fcW[c * 2 + k];
    }
    out[t] = acc;
  }
}

extern "C" void kernel_launch(void* const* d_in, const int* in_sizes, int n_in,
                              void* d_out, int out_size, void* d_ws, size_t ws_size,
                              hipStream_t stream) {
  const float* x = (const float*)d_in[0];
  const int* ei = (const int*)d_in[1];     // int32
  const int* batch = (const int*)d_in[2];  // int32 (sorted)
  const float* W1 = (const float*)d_in[3];
  const float* b1 = (const float*)d_in[4];
  const float* W2 = (const float*)d_in[5];
  const float* b2 = (const float*)d_in[6];
  const float* gamma = (const float*)d_in[7];
  const float* beta = (const float*)d_in[8];
  const float* fcW = (const float*)d_in[9];
  const float* fcb = (const float*)d_in[10];
  float* out = (float*)d_out;

  const int N = in_sizes[2];
  const int E = in_sizes[1] / 2;
  const int* srcp = ei;
  const int* dstp = ei + E;
  const int NB = (N + 255) >> BSHIFT;  // buckets (<=512 for N<=131072)

  // workspace layout (floats)
  float* ws = (float*)d_ws;
  size_t off = 0;
  auto alloc = [&](size_t n) {
    float* p = ws + off;
    off += (n + 127) & ~(size_t)127;
    return p;
  };
  int* row_ptr = (int*)alloc(N + 1);
  int* esrc = (int*)alloc(E);
  // records (E uints) region, later reused as xs (bf16 N x 64 = N*32 uints)
  size_t recsz = ((size_t)E > (size_t)N * 32 ? (size_t)E : (size_t)N * 32);
  float* recbuf = alloc(recsz);
  float* dis = alloc(N);
  float* y1b = alloc((size_t)N * 32);   // bf16 N x 64
  float* h1b = alloc((size_t)N * 64);   // bf16 N x 128
  float* h2b = alloc((size_t)N * 64);   // bf16 N x 128
  float* zb_ = alloc((size_t)N * 64);   // bf16 N x 128
  int* bbase = (int*)alloc(NBMAX + 1);
  int* bcursor = (int*)alloc(NBMAX);
  int* gstart = (int*)alloc(NGRAPH + 1);
  float* zero0 = ws + off;              // zeroed region start
  int* bcnt = (int*)alloc(NBMAX);
  float* gsum1 = alloc(NGRAPH * HID);
  float* gsq1 = alloc(NGRAPH * HID);
  float* gsum2 = alloc(NGRAPH * HID);
  float* gsq2 = alloc(NGRAPH * HID);
  float* pooled = alloc(NGRAPH * HID);
  size_t zero_bytes = (size_t)((ws + off) - zero0) * sizeof(float);
  float* cnt = alloc(NGRAPH);
  float* mean1 = alloc(NGRAPH * HID);
  float* inv1 = alloc(NGRAPH * HID);
  float* mean2 = alloc(NGRAPH * HID);
  float* inv2 = alloc(NGRAPH * HID);

  uint* records = (uint*)recbuf;
  ushort* xs = (ushort*)recbuf;  // alias: records dead after build_csr
  ushort* y1 = (ushort*)y1b;
  ushort* h1 = (ushort*)h1b;
  ushort* h2s = (ushort*)h2b;
  ushort* z = (ushort*)zb_;

  const int nblkN = (N + 255) / 256;
  const int nblkE4k = (E + 4095) / 4096;

  hipMemsetAsync(zero0, 0, zero_bytes, stream);

  // graph segments + CSR build
  graph_starts<<<nblkN, 256, 0, stream>>>(batch, gstart, N);
  cnt_from_starts<<<1, 64, 0, stream>>>(gstart, cnt);
  bucket_count<<<nblkE4k, 256, 0, stream>>>(dstp, bcnt, E, NB);
  bucket_scan<<<1, 512, 0, stream>>>(bcnt, bbase, bcursor, NB, E);
  bin_edges<<<nblkE4k, 256, 0, stream>>>(srcp, dstp, bcursor, records, E, NB);
  build_csr<<<NB, 256, 0, stream>>>(records, bbase, row_ptr, dis, esrc, N, E);

  const int aggBlocks = (N + 3) / 4;     // one wave per node
  const int gemmBlocks = (N + 63) / 64;  // 64 rows per block

  // ---- layer 1: xs = bf16(x*dis); y1 = A-hat x (bf16); h1 = y1 @ W1 + b1 (bf16) ----
  xscale_bf16<<<(N * 16 + 255) / 256, 256, 0, stream>>>(x, dis, xs, N * 16);
  aggregate64_bf16<<<aggBlocks, 256, 0, stream>>>(xs, row_ptr, esrc, dis, y1, N);
  gemm_tile<64, false, false><<<gemmBlocks, 256, 0, stream>>>(
      y1, W1, b1, nullptr, nullptr, nullptr, nullptr, h1, N);
  stats_pass<<<(N + 63) / 64, 256, 0, stream>>>(h1, batch, gsum1, gsq1, N);
  finalize_stats<<<(NGRAPH * HID + 255) / 256, 256, 0, stream>>>(gsum1, gsq1, cnt, mean1, inv1);

  // ---- layer 2: h2s = bf16(relu(norm(h1)) @ W2 * dis); z = A-hat h2 + b2 (bf16) ----
  gemm_tile<128, true, true><<<gemmBlocks, 256, 0, stream>>>(
      h1, W2, nullptr, batch, mean1, inv1, dis, h2s, N);
  aggregate128_bf16<<<aggBlocks, 256, 0, stream>>>(h2s, row_ptr, esrc, dis, b2, z, N);
  stats_pass<<<(N + 63) / 64, 256, 0, stream>>>(z, batch, gsum2, gsq2, N);
  finalize_stats<<<(NGRAPH * HID + 255) / 256, 256, 0, stream>>>(gsum2, gsq2, cnt, mean2, inv2);
  norm_relu_pool<<<(N + 63) / 64, 256, 0, stream>>>(z, batch, mean2, inv2, pooled, N);

  // ---- head ----
  final_head<<<1, 256, 0, stream>>>(pooled, cnt, gamma, beta, fcW, fcb, out);
}

// Round 11
// 329.727 us; speedup vs baseline: 1.6313x; 1.1067x over previous
//
#include <hip/hip_runtime.h>
#include <hip/hip_bf16.h>

// GCN classifier: N=100000, E=1.6M, IN=64, HID=128, 64 graphs, 2 classes.
// Round 10 (= round 9 minus the dead stub that broke compile): full-wave row
// gathers with 8-edge unroll (8 rows in flight; round-8 half-wave pairing cut
// MLP in half and regressed). Padded-bucket CSR (fixed cap per bucket) removes
// bucket_count + scan passes.

#define HID 128
#define NGRAPH 64
#define EPSN 1e-5f
#define BSHIFT 8            // 256 nodes per bucket
#define NBMAX 512

typedef unsigned int uint;
typedef unsigned short ushort;

static __device__ __forceinline__ ushort f2bf(float f) {  // round-nearest-even
  uint x = __float_as_uint(f);
  return (ushort)((x + 0x7FFFu + ((x >> 16) & 1u)) >> 16);
}
static __device__ __forceinline__ float bf_lo(uint u) { return __uint_as_float(u << 16); }
static __device__ __forceinline__ float bf_hi(uint u) {
  return __uint_as_float(u & 0xFFFF0000u);
}

// ---------------- per-graph segment boundaries (batch sorted) ----------------
__global__ __launch_bounds__(256) void graph_starts(const int* __restrict__ batch,
                                                    int* __restrict__ gstart, int N) {
  int i = blockIdx.x * 256 + threadIdx.x;
  if (i >= N) return;
  int g = batch[i];
  if (i == 0) {
    for (int q = 0; q <= g; ++q) gstart[q] = 0;
  } else {
    int gp = batch[i - 1];
    if (g != gp)
      for (int q = gp + 1; q <= g; ++q) gstart[q] = i;
  }
  if (i == N - 1)
    for (int q = g + 1; q <= NGRAPH; ++q) gstart[q] = N;
}

__global__ __launch_bounds__(64) void cnt_from_starts(const int* __restrict__ gstart,
                                                      float* __restrict__ cnt) {
  int g = threadIdx.x;
  if (g < NGRAPH) cnt[g] = (float)(gstart[g + 1] - gstart[g]);
}

// ---------------- padded-bucket counting sort: CSR build ----------------
__global__ __launch_bounds__(256) void init_cursor(int* __restrict__ gcursor, int NB, int cap) {
  int i = blockIdx.x * 256 + threadIdx.x;
  if (i < NB) gcursor[i] = i * cap;
}

// packed record: (src << 8) | (dst & 255)   [src < 2^24]
__global__ __launch_bounds__(256) void bin_edges(const int* __restrict__ src,
                                                 const int* __restrict__ dst,
                                                 int* __restrict__ gcursor,
                                                 uint* __restrict__ records, int E, int NB,
                                                 int cap) {
  __shared__ int h[NBMAX];
  __shared__ int base[NBMAX];
  for (int i = threadIdx.x; i < NB; i += 256) h[i] = 0;
  __syncthreads();
  int e0 = blockIdx.x * 4096;
  int d[16], s[16];
#pragma unroll
  for (int k = 0; k < 16; ++k) {
    int e = e0 + k * 256 + threadIdx.x;
    if (e < E) {
      d[k] = dst[e];
      s[k] = src[e];
      atomicAdd(&h[d[k] >> BSHIFT], 1);
    }
  }
  __syncthreads();
  for (int i = threadIdx.x; i < NB; i += 256) {
    int c = h[i];
    if (c) base[i] = atomicAdd(&gcursor[i], c);
  }
  __syncthreads();
  for (int i = threadIdx.x; i < NB; i += 256) h[i] = 0;  // reuse as local cursor
  __syncthreads();
#pragma unroll
  for (int k = 0; k < 16; ++k) {
    int e = e0 + k * 256 + threadIdx.x;
    if (e < E) {
      int b = d[k] >> BSHIFT;
      int lp = atomicAdd(&h[b], 1);
      records[base[b] + lp] = ((uint)s[k] << 8) | (uint)(d[k] & 255);
    }
  }
}

// one block per bucket: local count/scan -> row_beg/row_end, dis, esrc (padded).
__global__ __launch_bounds__(256) void build_csr(const uint* __restrict__ records,
                                                 const int* __restrict__ gcursor,
                                                 int* __restrict__ row_beg,
                                                 int* __restrict__ row_end,
                                                 float* __restrict__ dis,
                                                 int* __restrict__ esrc, int N, int cap) {
  const int b = blockIdx.x;
  const int node0 = b << BSHIFT;
  const int nn = min(256, N - node0);
  const int beg = b * cap;
  const int cnt = gcursor[b] - beg;
  const int t = threadIdx.x;
  __shared__ int lc[256], sc[256], lcur[256];
  lc[t] = 0;
  __syncthreads();
  for (int i = t; i < cnt; i += 256) atomicAdd(&lc[records[beg + i] & 255u], 1);
  __syncthreads();
  int myc = lc[t];
  sc[t] = myc;
  __syncthreads();
  for (int off = 1; off < 256; off <<= 1) {
    int add = (t >= off) ? sc[t - off] : 0;
    __syncthreads();
    sc[t] += add;
    __syncthreads();
  }
  int excl = sc[t] - myc;
  if (t < nn) {
    row_beg[node0 + t] = beg + excl;
    row_end[node0 + t] = beg + excl + myc;
    dis[node0 + t] = rsqrtf((float)myc + 1.0f);  // +1 self-loop
  }
  lcur[t] = excl;
  __syncthreads();
  for (int i = t; i < cnt; i += 256) {
    uint r = records[beg + i];
    int p = atomicAdd(&lcur[r & 255u], 1);
    esrc[beg + p] = (int)(r >> 8);
  }
}

// ---------------- xs = bf16(x * dis[row]) ----------------
__global__ __launch_bounds__(256) void xscale_bf16(const float* __restrict__ X,
                                                   const float* __restrict__ dis,
                                                   ushort* __restrict__ XS, int n4) {
  int i4 = blockIdx.x * 256 + threadIdx.x;  // unit = float4
  if (i4 >= n4) return;
  int n = i4 >> 4;  // 16 float4 per 64-ch row
  float dn = dis[n];
  float4 v = ((const float4*)X)[i4];
  ushort4 u;
  u.x = f2bf(v.x * dn);
  u.y = f2bf(v.y * dn);
  u.z = f2bf(v.z * dn);
  u.w = f2bf(v.w * dn);
  ((ushort4*)XS)[i4] = u;
}

// ---------------- aggregate 64-ch bf16 (prescaled), 8-edge unroll ----------------
// one wave per node; lane = 1 channel (2B), row = 128B, 8 rows in flight.
__global__ __launch_bounds__(256) void aggregate64(const ushort* __restrict__ XS,
                                                   const int* __restrict__ row_beg,
                                                   const int* __restrict__ row_end,
                                                   const int* __restrict__ esrc,
                                                   const float* __restrict__ dis,
                                                   ushort* __restrict__ out, int N) {
  int wid = (int)((blockIdx.x * 256 + threadIdx.x) >> 6);
  if (wid >= N) return;
  const int lane = threadIdx.x & 63;
  const float dn = dis[wid];
  const int beg = row_beg[wid];
  const int end = row_end[wid];
  const ushort* Xl = XS + lane;
  float a0 = 0.f, a1 = 0.f, a2 = 0.f, a3 = 0.f;
  int e = beg;
  for (; e + 7 < end; e += 8) {
    int s0 = esrc[e], s1 = esrc[e + 1], s2 = esrc[e + 2], s3 = esrc[e + 3];
    int s4 = esrc[e + 4], s5 = esrc[e + 5], s6 = esrc[e + 6], s7 = esrc[e + 7];
    ushort v0 = Xl[(size_t)s0 * 64];
    ushort v1 = Xl[(size_t)s1 * 64];
    ushort v2 = Xl[(size_t)s2 * 64];
    ushort v3 = Xl[(size_t)s3 * 64];
    ushort v4 = Xl[(size_t)s4 * 64];
    ushort v5 = Xl[(size_t)s5 * 64];
    ushort v6 = Xl[(size_t)s6 * 64];
    ushort v7 = Xl[(size_t)s7 * 64];
    a0 += __uint_as_float((uint)v0 << 16) + __uint_as_float((uint)v1 << 16);
    a1 += __uint_as_float((uint)v2 << 16) + __uint_as_float((uint)v3 << 16);
    a2 += __uint_as_float((uint)v4 << 16) + __uint_as_float((uint)v5 << 16);
    a3 += __uint_as_float((uint)v6 << 16) + __uint_as_float((uint)v7 << 16);
  }
  for (; e + 1 < end; e += 2) {
    ushort v0 = Xl[(size_t)esrc[e] * 64];
    ushort v1 = Xl[(size_t)esrc[e + 1] * 64];
    a0 += __uint_as_float((uint)v0 << 16);
    a1 += __uint_as_float((uint)v1 << 16);
  }
  if (e < end) a0 += __uint_as_float((uint)Xl[(size_t)esrc[e] * 64] << 16);
  a0 += a1 + a2 + a3 + __uint_as_float((uint)Xl[(size_t)wid * 64] << 16);  // + self
  out[(size_t)wid * 64 + lane] = f2bf(a0 * dn);
}

// ---------------- aggregate 128-ch bf16 (prescaled) + bias, 8-edge unroll ----------------
// one wave per node; lane = uint (2 ch), row = 256B, 8 rows in flight.
__global__ __launch_bounds__(256) void aggregate128(const ushort* __restrict__ H,
                                                    const int* __restrict__ row_beg,
                                                    const int* __restrict__ row_end,
                                                    const int* __restrict__ esrc,
                                                    const float* __restrict__ dis,
                                                    const float* __restrict__ bias,
                                                    ushort* __restrict__ outz, int N) {
  int wid = (int)((blockIdx.x * 256 + threadIdx.x) >> 6);
  if (wid >= N) return;
  const int lane = threadIdx.x & 63;
  const float dn = dis[wid];
  const int beg = row_beg[wid];
  const int end = row_end[wid];
  const uint* Hl = (const uint*)H + lane;  // 64 uints per row
  float a0 = 0.f, a1 = 0.f, b0 = 0.f, b1 = 0.f;
  float c0 = 0.f, c1 = 0.f, d0 = 0.f, d1 = 0.f;
  int e = beg;
  for (; e + 7 < end; e += 8) {
    int s0 = esrc[e], s1 = esrc[e + 1], s2 = esrc[e + 2], s3 = esrc[e + 3];
    int s4 = esrc[e + 4], s5 = esrc[e + 5], s6 = esrc[e + 6], s7 = esrc[e + 7];
    uint u0 = Hl[(size_t)s0 * 64];
    uint u1 = Hl[(size_t)s1 * 64];
    uint u2 = Hl[(size_t)s2 * 64];
    uint u3 = Hl[(size_t)s3 * 64];
    uint u4 = Hl[(size_t)s4 * 64];
    uint u5 = Hl[(size_t)s5 * 64];
    uint u6 = Hl[(size_t)s6 * 64];
    uint u7 = Hl[(size_t)s7 * 64];
    a0 += bf_lo(u0) + bf_lo(u1);
    a1 += bf_hi(u0) + bf_hi(u1);
    b0 += bf_lo(u2) + bf_lo(u3);
    b1 += bf_hi(u2) + bf_hi(u3);
    c0 += bf_lo(u4) + bf_lo(u5);
    c1 += bf_hi(u4) + bf_hi(u5);
    d0 += bf_lo(u6) + bf_lo(u7);
    d1 += bf_hi(u6) + bf_hi(u7);
  }
  for (; e + 1 < end; e += 2) {
    uint u0 = Hl[(size_t)esrc[e] * 64];
    uint u1 = Hl[(size_t)esrc[e + 1] * 64];
    a0 += bf_lo(u0);
    a1 += bf_hi(u0);
    b0 += bf_lo(u1);
    b1 += bf_hi(u1);
  }
  if (e < end) {
    uint u0 = Hl[(size_t)esrc[e] * 64];
    a0 += bf_lo(u0);
    a1 += bf_hi(u0);
  }
  uint us = Hl[(size_t)wid * 64];  // self (prescaled)
  a0 += b0 + c0 + d0 + bf_lo(us);
  a1 += b1 + c1 + d1 + bf_hi(us);
  float2 b = ((const float2*)bias)[lane];
  float r0 = a0 * dn + b.x;
  float r1 = a1 * dn + b.y;
  ((uint*)outz)[(size_t)wid * 64 + lane] = (uint)f2bf(r0) | ((uint)f2bf(r1) << 16);
}

// ---------------- GEMM tile: Y[N][128] = bf16X[N][K] @ W[K][128] (+bias) -> bf16 ----------------
template <int K, bool FUSE_NORM, bool DIS_SCALE>
__global__ __launch_bounds__(256) void gemm_tile(const ushort* __restrict__ X,
                                                 const float* __restrict__ W,
                                                 const float* __restrict__ bias,
                                                 const int* __restrict__ batch,
                                                 const float* __restrict__ mean,
                                                 const float* __restrict__ inv,
                                                 const float* __restrict__ disv,
                                                 ushort* __restrict__ Y, int N) {
  __shared__ float Xs[64][68];
  __shared__ float Ws[64][HID];
  const int t = threadIdx.x;
  const int r0 = (t >> 4) * 4;
  const int c0 = (t & 15) * 8;
  const int row0 = blockIdx.x * 64;
  float acc[4][8] = {};
  for (int k0 = 0; k0 < K; k0 += 64) {
    for (int i = t; i < 64 * 32; i += 256) {  // W: 64x128 in float4 units
      int kk = i >> 5;
      int c4 = i & 31;
      ((float4*)&Ws[kk][0])[c4] = ((const float4*)(W + (size_t)(k0 + kk) * HID))[c4];
    }
    for (int i = t; i < 64 * 8; i += 256) {  // X: 64 rows x 64 k, 16B (8 bf16) units
      int r = i >> 3;
      int u = i & 7;
      int gr = row0 + r;
      float f[8];
      if (gr < N) {
        uint4 v = *(const uint4*)(X + (size_t)gr * K + k0 + u * 8);
        f[0] = bf_lo(v.x);
        f[1] = bf_hi(v.x);
        f[2] = bf_lo(v.y);
        f[3] = bf_hi(v.y);
        f[4] = bf_lo(v.z);
        f[5] = bf_hi(v.z);
        f[6] = bf_lo(v.w);
        f[7] = bf_hi(v.w);
        if (FUSE_NORM) {
          int g = batch[gr];
          const float* mp = mean + g * HID + k0 + u * 8;
          const float* ip = inv + g * HID + k0 + u * 8;
#pragma unroll
          for (int j = 0; j < 8; ++j) f[j] = fmaxf((f[j] - mp[j]) * ip[j], 0.f);
        }
      } else {
#pragma unroll
        for (int j = 0; j < 8; ++j) f[j] = 0.f;
      }
#pragma unroll
      for (int j = 0; j < 8; ++j) Xs[r][u * 8 + j] = f[j];
    }
    __syncthreads();
#pragma unroll 4
    for (int kk = 0; kk < 64; ++kk) {
      float4 w0 = *(const float4*)&Ws[kk][c0];
      float4 w1 = *(const float4*)&Ws[kk][c0 + 4];
      float xr[4];
#pragma unroll
      for (int i = 0; i < 4; ++i) xr[i] = Xs[r0 + i][kk];
#pragma unroll
      for (int i = 0; i < 4; ++i) {
        acc[i][0] += xr[i] * w0.x;
        acc[i][1] += xr[i] * w0.y;
        acc[i][2] += xr[i] * w0.z;
        acc[i][3] += xr[i] * w0.w;
        acc[i][4] += xr[i] * w1.x;
        acc[i][5] += xr[i] * w1.y;
        acc[i][6] += xr[i] * w1.z;
        acc[i][7] += xr[i] * w1.w;
      }
    }
    __syncthreads();
  }
  float bv[8];
#pragma unroll
  for (int j = 0; j < 8; ++j) bv[j] = bias ? bias[c0 + j] : 0.f;
#pragma unroll
  for (int i = 0; i < 4; ++i) {
    int gr = row0 + r0 + i;
    if (gr < N) {
      float ds = DIS_SCALE ? disv[gr] : 1.f;
      uint4 u;
      u.x = (uint)f2bf((acc[i][0] + bv[0]) * ds) | ((uint)f2bf((acc[i][1] + bv[1]) * ds) << 16);
      u.y = (uint)f2bf((acc[i][2] + bv[2]) * ds) | ((uint)f2bf((acc[i][3] + bv[3]) * ds) << 16);
      u.z = (uint)f2bf((acc[i][4] + bv[4]) * ds) | ((uint)f2bf((acc[i][5] + bv[5]) * ds) << 16);
      u.w = (uint)f2bf((acc[i][6] + bv[6]) * ds) | ((uint)f2bf((acc[i][7] + bv[7]) * ds) << 16);
      *(uint4*)(Y + (size_t)gr * HID + c0) = u;
    }
  }
}

// ---------------- per-graph sum/sumsq (bf16 input) ----------------
__global__ __launch_bounds__(256) void stats_pass(const ushort* __restrict__ G,
                                                  const int* __restrict__ batch,
                                                  float* __restrict__ gsum,
                                                  float* __restrict__ gsq, int N) {
  const int c = threadIdx.x & 127;
  const int half = threadIdx.x >> 7;
  const int n0 = blockIdx.x * 64 + half * 32;
  const int n1 = min(n0 + 32, N);
  float s = 0.f, sq = 0.f;
  int cur = -1;
  for (int n = n0; n < n1; ++n) {
    int g = batch[n];
    if (g != cur) {
      if (cur >= 0) {
        atomicAdd(&gsum[cur * HID + c], s);
        atomicAdd(&gsq[cur * HID + c], sq);
      }
      cur = g;
      s = 0.f;
      sq = 0.f;
    }
    float val = __uint_as_float((uint)G[(size_t)n * HID + c] << 16);
    s += val;
    sq += val * val;
  }
  if (cur >= 0) {
    atomicAdd(&gsum[cur * HID + c], s);
    atomicAdd(&gsq[cur * HID + c], sq);
  }
}

__global__ __launch_bounds__(256) void finalize_stats(const float* __restrict__ gsum,
                                                      const float* __restrict__ gsq,
                                                      const float* __restrict__ cnt,
                                                      float* __restrict__ mean,
                                                      float* __restrict__ inv) {
  int i = blockIdx.x * 256 + threadIdx.x;
  if (i >= NGRAPH * HID) return;
  int g = i >> 7;
  float c = fmaxf(cnt[g], 1.f);
  float m = gsum[i] / c;
  float v = gsq[i] / c - m * m;
  mean[i] = m;
  inv[i] = rsqrtf(v + EPSN);
}

__global__ __launch_bounds__(256) void norm_relu_pool(const ushort* __restrict__ G,
                                                      const int* __restrict__ batch,
                                                      const float* __restrict__ mean,
                                                      const float* __restrict__ inv,
                                                      float* __restrict__ pooled, int N) {
  const int c = threadIdx.x & 127;
  const int half = threadIdx.x >> 7;
  const int n0 = blockIdx.x * 64 + half * 32;
  const int n1 = min(n0 + 32, N);
  float s = 0.f;
  int cur = -1;
  for (int n = n0; n < n1; ++n) {
    int g = batch[n];
    if (g != cur) {
      if (cur >= 0) atomicAdd(&pooled[cur * HID + c], s);
      cur = g;
      s = 0.f;
    }
    float val = __uint_as_float((uint)G[(size_t)n * HID + c] << 16);
    float v = (val - mean[g * HID + c]) * inv[g * HID + c];
    s += fmaxf(v, 0.f);
  }
  if (cur >= 0) atomicAdd(&pooled[cur * HID + c], s);
}

// ---------------- final head ----------------
__global__ __launch_bounds__(256) void final_head(const float* __restrict__ pooled_sum,
                                                  const float* __restrict__ cnt,
                                                  const float* __restrict__ gamma,
                                                  const float* __restrict__ beta,
                                                  const float* __restrict__ fcW,
                                                  const float* __restrict__ fcb,
                                                  float* __restrict__ out) {
  __shared__ float P[NGRAPH][HID];
  __shared__ float zs[HID], zb[HID];
  int t = threadIdx.x;
  for (int i = t; i < NGRAPH * HID; i += 256) {
    int g = i >> 7;
    P[g][i & 127] = pooled_sum[i] / fmaxf(cnt[g], 1.f);
  }
  __syncthreads();
  if (t < HID) {
    float m = 0.f;
    for (int g = 0; g < NGRAPH; ++g) m += P[g][t];
    m *= (1.f / NGRAPH);
    float v = 0.f;
    for (int g = 0; g < NGRAPH; ++g) {
      float d = P[g][t] - m;
      v += d * d;
    }
    v *= (1.f / NGRAPH);
    float sc = rsqrtf(v + EPSN) * gamma[t];
    zs[t] = sc;
    zb[t] = beta[t] - m * sc;
  }
  __syncthreads();
  if (t < NGRAPH * 2) {
    int g = t >> 1, k = t & 1;
    float acc = fcb[k];
    for (int c = 0; c < HID; ++c) {
      float z = P[g][c] * zs[c] + zb[c];
      acc += z * fcW[c * 2 + k];
    }
    out[t] = acc;
  }
}

extern "C" void kernel_launch(void* const* d_in, const int* in_sizes, int n_in,
                              void* d_out, int out_size, void* d_ws, size_t ws_size,
                              hipStream_t stream) {
  const float* x = (const float*)d_in[0];
  const int* ei = (const int*)d_in[1];     // int32
  const int* batch = (const int*)d_in[2];  // int32 (sorted)
  const float* W1 = (const float*)d_in[3];
  const float* b1 = (const float*)d_in[4];
  const float* W2 = (const float*)d_in[5];
  const float* b2 = (const float*)d_in[6];
  const float* gamma = (const float*)d_in[7];
  const float* beta = (const float*)d_in[8];
  const float* fcW = (const float*)d_in[9];
  const float* fcb = (const float*)d_in[10];
  float* out = (float*)d_out;

  const int N = in_sizes[2];
  const int E = in_sizes[1] / 2;
  const int* srcp = ei;
  const int* dstp = ei + E;
  const int NB = (N + 255) >> BSHIFT;       // buckets (<=512 for N<=131072)
  const int cap = 2 * (E / NB) + 256;       // per-bucket capacity (~64 sigma margin)

  // workspace layout (floats)
  float* ws = (float*)d_ws;
  size_t off = 0;
  auto alloc = [&](size_t n) {
    float* p = ws + off;
    off += (n + 127) & ~(size_t)127;
    return p;
  };
  int* row_beg = (int*)alloc(N);
  int* row_end = (int*)alloc(N);
  int* esrc = (int*)alloc((size_t)NB * cap);
  // records (NB*cap uints) region, later reused as xs (bf16 N x 64 = N*32 uints)
  size_t recsz = ((size_t)NB * cap > (size_t)N * 32 ? (size_t)NB * cap : (size_t)N * 32);
  float* recbuf = alloc(recsz);
  float* dis = alloc(N);
  float* y1b = alloc((size_t)N * 32);   // bf16 N x 64
  float* h1b = alloc((size_t)N * 64);   // bf16 N x 128
  float* h2b = alloc((size_t)N * 64);   // bf16 N x 128
  float* zb_ = alloc((size_t)N * 64);   // bf16 N x 128
  int* gcursor = (int*)alloc(NBMAX);
  int* gstart = (int*)alloc(NGRAPH + 1);
  float* zero0 = ws + off;              // zeroed region start
  float* gsum1 = alloc(NGRAPH * HID);
  float* gsq1 = alloc(NGRAPH * HID);
  float* gsum2 = alloc(NGRAPH * HID);
  float* gsq2 = alloc(NGRAPH * HID);
  float* pooled = alloc(NGRAPH * HID);
  size_t zero_bytes = (size_t)((ws + off) - zero0) * sizeof(float);
  float* cnt = alloc(NGRAPH);
  float* mean1 = alloc(NGRAPH * HID);
  float* inv1 = alloc(NGRAPH * HID);
  float* mean2 = alloc(NGRAPH * HID);
  float* inv2 = alloc(NGRAPH * HID);

  uint* records = (uint*)recbuf;
  ushort* xs = (ushort*)recbuf;  // alias: records dead after build_csr
  ushort* y1 = (ushort*)y1b;
  ushort* h1 = (ushort*)h1b;
  ushort* h2s = (ushort*)h2b;
  ushort* z = (ushort*)zb_;

  const int nblkN = (N + 255) / 256;
  const int nblkE4k = (E + 4095) / 4096;

  hipMemsetAsync(zero0, 0, zero_bytes, stream);

  // graph segments + padded CSR build
  graph_starts<<<nblkN, 256, 0, stream>>>(batch, gstart, N);
  cnt_from_starts<<<1, 64, 0, stream>>>(gstart, cnt);
  init_cursor<<<(NB + 255) / 256, 256, 0, stream>>>(gcursor, NB, cap);
  bin_edges<<<nblkE4k, 256, 0, stream>>>(srcp, dstp, gcursor, records, E, NB, cap);
  build_csr<<<NB, 256, 0, stream>>>(records, gcursor, row_beg, row_end, dis, esrc, N, cap);

  const int aggBlocks = (N + 3) / 4;     // one wave per node
  const int gemmBlocks = (N + 63) / 64;  // 64 rows per block

  // ---- layer 1: xs = bf16(x*dis); y1 = A-hat x (bf16); h1 = y1 @ W1 + b1 (bf16) ----
  xscale_bf16<<<(N * 16 + 255) / 256, 256, 0, stream>>>(x, dis, xs, N * 16);
  aggregate64<<<aggBlocks, 256, 0, stream>>>(xs, row_beg, row_end, esrc, dis, y1, N);
  gemm_tile<64, false, false><<<gemmBlocks, 256, 0, stream>>>(
      y1, W1, b1, nullptr, nullptr, nullptr, nullptr, h1, N);
  stats_pass<<<(N + 63) / 64, 256, 0, stream>>>(h1, batch, gsum1, gsq1, N);
  finalize_stats<<<(NGRAPH * HID + 255) / 256, 256, 0, stream>>>(gsum1, gsq1, cnt, mean1, inv1);

  // ---- layer 2: h2s = bf16(relu(norm(h1)) @ W2 * dis); z = A-hat h2 + b2 (bf16) ----
  gemm_tile<128, true, true><<<gemmBlocks, 256, 0, stream>>>(
      h1, W2, nullptr, batch, mean1, inv1, dis, h2s, N);
  aggregate128<<<aggBlocks, 256, 0, stream>>>(h2s, row_beg, row_end, esrc, dis, b2, z, N);
  stats_pass<<<(N + 63) / 64, 256, 0, stream>>>(z, batch, gsum2, gsq2, N);
  finalize_stats<<<(NGRAPH * HID + 255) / 256, 256, 0, stream>>>(gsum2, gsq2, cnt, mean2, inv2);
  norm_relu_pool<<<(N + 63) / 64, 256, 0, stream>>>(z, batch, mean2, inv2, pooled, N);

  // ---- head ----
  final_head<<<1, 256, 0, stream>>>(pooled, cnt, gamma, beta, fcW, fcb, out);
}

// Round 12
// 307.608 us; speedup vs baseline: 1.7486x; 1.0719x over previous
//
#include <hip/hip_runtime.h>
#include <hip/hip_bf16.h>

// GCN classifier: N=100000, E=1.6M, IN=64, HID=128, 64 graphs, 2 classes.
// Round 12: bf16 MFMA GEMMs (16x16x32). A-frag direct from global (row=l&15,
// k=(l>>4)*8), B-frag from col-major bf16 Wt (one-time transpose). Layer-2
// norm+relu applied in-register on the A-frag. Aggregation kernels unchanged
// (agg128 at per-XCD compulsory-fetch floor, 192MB = 8 XCD x 25.6MB).

#define HID 128
#define NGRAPH 64
#define EPSN 1e-5f
#define BSHIFT 8            // 256 nodes per bucket
#define NBMAX 512

typedef unsigned int uint;
typedef unsigned short ushort;
typedef __attribute__((ext_vector_type(8))) short short8;   // 8 bf16 (4 VGPRs)
typedef __attribute__((ext_vector_type(4))) float f32x4;    // MFMA accumulator

static __device__ __forceinline__ ushort f2bf(float f) {  // round-nearest-even
  uint x = __float_as_uint(f);
  return (ushort)((x + 0x7FFFu + ((x >> 16) & 1u)) >> 16);
}
static __device__ __forceinline__ float bf_lo(uint u) { return __uint_as_float(u << 16); }
static __device__ __forceinline__ float bf_hi(uint u) {
  return __uint_as_float(u & 0xFFFF0000u);
}

// ---------------- per-graph segment boundaries (batch sorted) ----------------
__global__ __launch_bounds__(256) void graph_starts(const int* __restrict__ batch,
                                                    int* __restrict__ gstart, int N) {
  int i = blockIdx.x * 256 + threadIdx.x;
  if (i >= N) return;
  int g = batch[i];
  if (i == 0) {
    for (int q = 0; q <= g; ++q) gstart[q] = 0;
  } else {
    int gp = batch[i - 1];
    if (g != gp)
      for (int q = gp + 1; q <= g; ++q) gstart[q] = i;
  }
  if (i == N - 1)
    for (int q = g + 1; q <= NGRAPH; ++q) gstart[q] = N;
}

__global__ __launch_bounds__(64) void cnt_from_starts(const int* __restrict__ gstart,
                                                      float* __restrict__ cnt) {
  int g = threadIdx.x;
  if (g < NGRAPH) cnt[g] = (float)(gstart[g + 1] - gstart[g]);
}

// ---------------- padded-bucket counting sort: CSR build ----------------
__global__ __launch_bounds__(256) void init_cursor(int* __restrict__ gcursor, int NB, int cap) {
  int i = blockIdx.x * 256 + threadIdx.x;
  if (i < NB) gcursor[i] = i * cap;
}

// packed record: (src << 8) | (dst & 255)   [src < 2^24]
__global__ __launch_bounds__(256) void bin_edges(const int* __restrict__ src,
                                                 const int* __restrict__ dst,
                                                 int* __restrict__ gcursor,
                                                 uint* __restrict__ records, int E, int NB,
                                                 int cap) {
  __shared__ int h[NBMAX];
  __shared__ int base[NBMAX];
  for (int i = threadIdx.x; i < NB; i += 256) h[i] = 0;
  __syncthreads();
  int e0 = blockIdx.x * 4096;
  int d[16], s[16];
#pragma unroll
  for (int k = 0; k < 16; ++k) {
    int e = e0 + k * 256 + threadIdx.x;
    if (e < E) {
      d[k] = dst[e];
      s[k] = src[e];
      atomicAdd(&h[d[k] >> BSHIFT], 1);
    }
  }
  __syncthreads();
  for (int i = threadIdx.x; i < NB; i += 256) {
    int c = h[i];
    if (c) base[i] = atomicAdd(&gcursor[i], c);
  }
  __syncthreads();
  for (int i = threadIdx.x; i < NB; i += 256) h[i] = 0;  // reuse as local cursor
  __syncthreads();
#pragma unroll
  for (int k = 0; k < 16; ++k) {
    int e = e0 + k * 256 + threadIdx.x;
    if (e < E) {
      int b = d[k] >> BSHIFT;
      int lp = atomicAdd(&h[b], 1);
      records[base[b] + lp] = ((uint)s[k] << 8) | (uint)(d[k] & 255);
    }
  }
}

// one block per bucket: local count/scan -> row_beg/row_end, dis, esrc (padded).
__global__ __launch_bounds__(256) void build_csr(const uint* __restrict__ records,
                                                 const int* __restrict__ gcursor,
                                                 int* __restrict__ row_beg,
                                                 int* __restrict__ row_end,
                                                 float* __restrict__ dis,
                                                 int* __restrict__ esrc, int N, int cap) {
  const int b = blockIdx.x;
  const int node0 = b << BSHIFT;
  const int nn = min(256, N - node0);
  const int beg = b * cap;
  const int cnt = gcursor[b] - beg;
  const int t = threadIdx.x;
  __shared__ int lc[256], sc[256], lcur[256];
  lc[t] = 0;
  __syncthreads();
  for (int i = t; i < cnt; i += 256) atomicAdd(&lc[records[beg + i] & 255u], 1);
  __syncthreads();
  int myc = lc[t];
  sc[t] = myc;
  __syncthreads();
  for (int off = 1; off < 256; off <<= 1) {
    int add = (t >= off) ? sc[t - off] : 0;
    __syncthreads();
    sc[t] += add;
    __syncthreads();
  }
  int excl = sc[t] - myc;
  if (t < nn) {
    row_beg[node0 + t] = beg + excl;
    row_end[node0 + t] = beg + excl + myc;
    dis[node0 + t] = rsqrtf((float)myc + 1.0f);  // +1 self-loop
  }
  lcur[t] = excl;
  __syncthreads();
  for (int i = t; i < cnt; i += 256) {
    uint r = records[beg + i];
    int p = atomicAdd(&lcur[r & 255u], 1);
    esrc[beg + p] = (int)(r >> 8);
  }
}

// ---------------- xs = bf16(x * dis[row]) ----------------
__global__ __launch_bounds__(256) void xscale_bf16(const float* __restrict__ X,
                                                   const float* __restrict__ dis,
                                                   ushort* __restrict__ XS, int n4) {
  int i4 = blockIdx.x * 256 + threadIdx.x;  // unit = float4
  if (i4 >= n4) return;
  int n = i4 >> 4;  // 16 float4 per 64-ch row
  float dn = dis[n];
  float4 v = ((const float4*)X)[i4];
  ushort4 u;
  u.x = f2bf(v.x * dn);
  u.y = f2bf(v.y * dn);
  u.z = f2bf(v.z * dn);
  u.w = f2bf(v.w * dn);
  ((ushort4*)XS)[i4] = u;
}

// ---------------- W (K x 128 fp32, row-major) -> Wt (128 x K bf16, col-major) ----------------
template <int K>
__global__ __launch_bounds__(256) void wt_bf16(const float* __restrict__ W,
                                               ushort* __restrict__ Wt) {
  int i = blockIdx.x * 256 + threadIdx.x;  // i = c*K + k
  if (i >= 128 * K) return;
  int c = i / K;
  int k = i - c * K;
  Wt[i] = f2bf(W[(size_t)k * HID + c]);
}

// ---------------- aggregate 64-ch bf16 (prescaled), 8-edge unroll ----------------
__global__ __launch_bounds__(256) void aggregate64(const ushort* __restrict__ XS,
                                                   const int* __restrict__ row_beg,
                                                   const int* __restrict__ row_end,
                                                   const int* __restrict__ esrc,
                                                   const float* __restrict__ dis,
                                                   ushort* __restrict__ out, int N) {
  int wid = (int)((blockIdx.x * 256 + threadIdx.x) >> 6);
  if (wid >= N) return;
  const int lane = threadIdx.x & 63;
  const float dn = dis[wid];
  const int beg = row_beg[wid];
  const int end = row_end[wid];
  const ushort* Xl = XS + lane;
  float a0 = 0.f, a1 = 0.f, a2 = 0.f, a3 = 0.f;
  int e = beg;
  for (; e + 7 < end; e += 8) {
    int s0 = esrc[e], s1 = esrc[e + 1], s2 = esrc[e + 2], s3 = esrc[e + 3];
    int s4 = esrc[e + 4], s5 = esrc[e + 5], s6 = esrc[e + 6], s7 = esrc[e + 7];
    ushort v0 = Xl[(size_t)s0 * 64];
    ushort v1 = Xl[(size_t)s1 * 64];
    ushort v2 = Xl[(size_t)s2 * 64];
    ushort v3 = Xl[(size_t)s3 * 64];
    ushort v4 = Xl[(size_t)s4 * 64];
    ushort v5 = Xl[(size_t)s5 * 64];
    ushort v6 = Xl[(size_t)s6 * 64];
    ushort v7 = Xl[(size_t)s7 * 64];
    a0 += __uint_as_float((uint)v0 << 16) + __uint_as_float((uint)v1 << 16);
    a1 += __uint_as_float((uint)v2 << 16) + __uint_as_float((uint)v3 << 16);
    a2 += __uint_as_float((uint)v4 << 16) + __uint_as_float((uint)v5 << 16);
    a3 += __uint_as_float((uint)v6 << 16) + __uint_as_float((uint)v7 << 16);
  }
  for (; e + 1 < end; e += 2) {
    ushort v0 = Xl[(size_t)esrc[e] * 64];
    ushort v1 = Xl[(size_t)esrc[e + 1] * 64];
    a0 += __uint_as_float((uint)v0 << 16);
    a1 += __uint_as_float((uint)v1 << 16);
  }
  if (e < end) a0 += __uint_as_float((uint)Xl[(size_t)esrc[e] * 64] << 16);
  a0 += a1 + a2 + a3 + __uint_as_float((uint)Xl[(size_t)wid * 64] << 16);  // + self
  out[(size_t)wid * 64 + lane] = f2bf(a0 * dn);
}

// ---------------- aggregate 128-ch bf16 (prescaled) + bias, 8-edge unroll ----------------
__global__ __launch_bounds__(256) void aggregate128(const ushort* __restrict__ H,
                                                    const int* __restrict__ row_beg,
                                                    const int* __restrict__ row_end,
                                                    const int* __restrict__ esrc,
                                                    const float* __restrict__ dis,
                                                    const float* __restrict__ bias,
                                                    ushort* __restrict__ outz, int N) {
  int wid = (int)((blockIdx.x * 256 + threadIdx.x) >> 6);
  if (wid >= N) return;
  const int lane = threadIdx.x & 63;
  const float dn = dis[wid];
  const int beg = row_beg[wid];
  const int end = row_end[wid];
  const uint* Hl = (const uint*)H + lane;  // 64 uints per row
  float a0 = 0.f, a1 = 0.f, b0 = 0.f, b1 = 0.f;
  float c0 = 0.f, c1 = 0.f, d0 = 0.f, d1 = 0.f;
  int e = beg;
  for (; e + 7 < end; e += 8) {
    int s0 = esrc[e], s1 = esrc[e + 1], s2 = esrc[e + 2], s3 = esrc[e + 3];
    int s4 = esrc[e + 4], s5 = esrc[e + 5], s6 = esrc[e + 6], s7 = esrc[e + 7];
    uint u0 = Hl[(size_t)s0 * 64];
    uint u1 = Hl[(size_t)s1 * 64];
    uint u2 = Hl[(size_t)s2 * 64];
    uint u3 = Hl[(size_t)s3 * 64];
    uint u4 = Hl[(size_t)s4 * 64];
    uint u5 = Hl[(size_t)s5 * 64];
    uint u6 = Hl[(size_t)s6 * 64];
    uint u7 = Hl[(size_t)s7 * 64];
    a0 += bf_lo(u0) + bf_lo(u1);
    a1 += bf_hi(u0) + bf_hi(u1);
    b0 += bf_lo(u2) + bf_lo(u3);
    b1 += bf_hi(u2) + bf_hi(u3);
    c0 += bf_lo(u4) + bf_lo(u5);
    c1 += bf_hi(u4) + bf_hi(u5);
    d0 += bf_lo(u6) + bf_lo(u7);
    d1 += bf_hi(u6) + bf_hi(u7);
  }
  for (; e + 1 < end; e += 2) {
    uint u0 = Hl[(size_t)esrc[e] * 64];
    uint u1 = Hl[(size_t)esrc[e + 1] * 64];
    a0 += bf_lo(u0);
    a1 += bf_hi(u0);
    b0 += bf_lo(u1);
    b1 += bf_hi(u1);
  }
  if (e < end) {
    uint u0 = Hl[(size_t)esrc[e] * 64];
    a0 += bf_lo(u0);
    a1 += bf_hi(u0);
  }
  uint us = Hl[(size_t)wid * 64];  // self (prescaled)
  a0 += b0 + c0 + d0 + bf_lo(us);
  a1 += b1 + c1 + d1 + bf_hi(us);
  float2 b = ((const float2*)bias)[lane];
  float r0 = a0 * dn + b.x;
  float r1 = a1 * dn + b.y;
  ((uint*)outz)[(size_t)wid * 64 + lane] = (uint)f2bf(r0) | ((uint)f2bf(r1) << 16);
}

// ---------------- MFMA GEMM: Y[N][128] = bf16X[N][K] @ W[K][128] -> bf16 ----------------
// Block: 64 rows, 4 waves; wave w computes rows row0+w*16..+15, all 128 cols.
// A-frag: lane l holds X[row0w + (l&15)][k0 + (l>>4)*8 + j], j=0..7 (16B contiguous).
// B-frag: Wt col-major [128][K] bf16 -> Wt[(nf*16+(l&15))*K + k0 + (l>>4)*8 + j].
// C/D: col = lane&15, row = (lane>>4)*4 + reg (m89-verified layout).
template <int K, bool FUSE_NORM, bool DIS_SCALE, bool HAS_BIAS>
__global__ __launch_bounds__(256) void gemm_mfma(const ushort* __restrict__ X,
                                                 const ushort* __restrict__ Wt,
                                                 const float* __restrict__ bias,
                                                 const int* __restrict__ batch,
                                                 const float* __restrict__ mean,
                                                 const float* __restrict__ inv,
                                                 const float* __restrict__ disv,
                                                 ushort* __restrict__ Y, int N) {
  const int t = threadIdx.x;
  const int w = t >> 6;
  const int l = t & 63;
  const int lr = l & 15;   // A row / B-D col within tile
  const int lk = l >> 4;   // k-group 0..3 (also D row group)
  const int row0 = blockIdx.x * 64 + w * 16;
  const int arow = min(row0 + lr, N - 1);  // clamp: OOB rows produce discarded C rows
  int g = 0;
  if (FUSE_NORM) g = batch[arow];
  f32x4 acc[8];
#pragma unroll
  for (int i = 0; i < 8; ++i) acc[i] = (f32x4){0.f, 0.f, 0.f, 0.f};
#pragma unroll
  for (int k0 = 0; k0 < K; k0 += 32) {
    const int kbase = k0 + lk * 8;
    short8 a = *(const short8*)(X + (size_t)arow * K + kbase);
    if (FUSE_NORM) {
      const float* mp = mean + g * HID + kbase;
      const float* ip = inv + g * HID + kbase;
      short8 an;
#pragma unroll
      for (int j = 0; j < 8; ++j) {
        float f = __uint_as_float((uint)(ushort)a[j] << 16);
        f = fmaxf((f - mp[j]) * ip[j], 0.f);
        an[j] = (short)f2bf(f);
      }
      a = an;
    }
#pragma unroll
    for (int nf = 0; nf < 8; ++nf) {
      short8 b = *(const short8*)(Wt + (size_t)(nf * 16 + lr) * K + kbase);
      acc[nf] = __builtin_amdgcn_mfma_f32_16x16x32_bf16(a, b, acc[nf], 0, 0, 0);
    }
  }
#pragma unroll
  for (int r = 0; r < 4; ++r) {
    int grow = row0 + lk * 4 + r;
    if (grow < N) {
      float ds = DIS_SCALE ? disv[grow] : 1.f;
#pragma unroll
      for (int nf = 0; nf < 8; ++nf) {
        int col = nf * 16 + lr;
        float v = acc[nf][r];
        if (HAS_BIAS) v += bias[col];
        v *= ds;
        Y[(size_t)grow * HID + col] = f2bf(v);
      }
    }
  }
}

// ---------------- per-graph sum/sumsq (bf16 input) ----------------
__global__ __launch_bounds__(256) void stats_pass(const ushort* __restrict__ G,
                                                  const int* __restrict__ batch,
                                                  float* __restrict__ gsum,
                                                  float* __restrict__ gsq, int N) {
  const int c = threadIdx.x & 127;
  const int half = threadIdx.x >> 7;
  const int n0 = blockIdx.x * 64 + half * 32;
  const int n1 = min(n0 + 32, N);
  float s = 0.f, sq = 0.f;
  int cur = -1;
  for (int n = n0; n < n1; ++n) {
    int g = batch[n];
    if (g != cur) {
      if (cur >= 0) {
        atomicAdd(&gsum[cur * HID + c], s);
        atomicAdd(&gsq[cur * HID + c], sq);
      }
      cur = g;
      s = 0.f;
      sq = 0.f;
    }
    float val = __uint_as_float((uint)G[(size_t)n * HID + c] << 16);
    s += val;
    sq += val * val;
  }
  if (cur >= 0) {
    atomicAdd(&gsum[cur * HID + c], s);
    atomicAdd(&gsq[cur * HID + c], sq);
  }
}

__global__ __launch_bounds__(256) void finalize_stats(const float* __restrict__ gsum,
                                                      const float* __restrict__ gsq,
                                                      const float* __restrict__ cnt,
                                                      float* __restrict__ mean,
                                                      float* __restrict__ inv) {
  int i = blockIdx.x * 256 + threadIdx.x;
  if (i >= NGRAPH * HID) return;
  int g = i >> 7;
  float c = fmaxf(cnt[g], 1.f);
  float m = gsum[i] / c;
  float v = gsq[i] / c - m * m;
  mean[i] = m;
  inv[i] = rsqrtf(v + EPSN);
}

__global__ __launch_bounds__(256) void norm_relu_pool(const ushort* __restrict__ G,
                                                      const int* __restrict__ batch,
                                                      const float* __restrict__ mean,
                                                      const float* __restrict__ inv,
                                                      float* __restrict__ pooled, int N) {
  const int c = threadIdx.x & 127;
  const int half = threadIdx.x >> 7;
  const int n0 = blockIdx.x * 64 + half * 32;
  const int n1 = min(n0 + 32, N);
  float s = 0.f;
  int cur = -1;
  for (int n = n0; n < n1; ++n) {
    int g = batch[n];
    if (g != cur) {
      if (cur >= 0) atomicAdd(&pooled[cur * HID + c], s);
      cur = g;
      s = 0.f;
    }
    float val = __uint_as_float((uint)G[(size_t)n * HID + c] << 16);
    float v = (val - mean[g * HID + c]) * inv[g * HID + c];
    s += fmaxf(v, 0.f);
  }
  if (cur >= 0) atomicAdd(&pooled[cur * HID + c], s);
}

// ---------------- final head ----------------
__global__ __launch_bounds__(256) void final_head(const float* __restrict__ pooled_sum,
                                                  const float* __restrict__ cnt,
                                                  const float* __restrict__ gamma,
                                                  const float* __restrict__ beta,
                                                  const float* __restrict__ fcW,
                                                  const float* __restrict__ fcb,
                                                  float* __restrict__ out) {
  __shared__ float P[NGRAPH][HID];
  __shared__ float zs[HID], zb[HID];
  int t = threadIdx.x;
  for (int i = t; i < NGRAPH * HID; i += 256) {
    int g = i >> 7;
    P[g][i & 127] = pooled_sum[i] / fmaxf(cnt[g], 1.f);
  }
  __syncthreads();
  if (t < HID) {
    float m = 0.f;
    for (int g = 0; g < NGRAPH; ++g) m += P[g][t];
    m *= (1.f / NGRAPH);
    float v = 0.f;
    for (int g = 0; g < NGRAPH; ++g) {
      float d = P[g][t] - m;
      v += d * d;
    }
    v *= (1.f / NGRAPH);
    float sc = rsqrtf(v + EPSN) * gamma[t];
    zs[t] = sc;
    zb[t] = beta[t] - m * sc;
  }
  __syncthreads();
  if (t < NGRAPH * 2) {
    int g = t >> 1, k = t & 1;
    float acc = fcb[k];
    for (int c = 0; c < HID; ++c) {
      float z = P[g][c] * zs[c] + zb[c];
      acc += z * fcW[c * 2 + k];
    }
    out[t] = acc;
  }
}

extern "C" void kernel_launch(void* const* d_in, const int* in_sizes, int n_in,
                              void* d_out, int out_size, void* d_ws, size_t ws_size,
                              hipStream_t stream) {
  const float* x = (const float*)d_in[0];
  const int* ei = (const int*)d_in[1];     // int32
  const int* batch = (const int*)d_in[2];  // int32 (sorted)
  const float* W1 = (const float*)d_in[3];
  const float* b1 = (const float*)d_in[4];
  const float* W2 = (const float*)d_in[5];
  const float* b2 = (const float*)d_in[6];
  const float* gamma = (const float*)d_in[7];
  const float* beta = (const float*)d_in[8];
  const float* fcW = (const float*)d_in[9];
  const float* fcb = (const float*)d_in[10];
  float* out = (float*)d_out;

  const int N = in_sizes[2];
  const int E = in_sizes[1] / 2;
  const int* srcp = ei;
  const int* dstp = ei + E;
  const int NB = (N + 255) >> BSHIFT;       // buckets (<=512 for N<=131072)
  const int cap = 2 * (E / NB) + 256;       // per-bucket capacity (~64 sigma margin)

  // workspace layout (floats)
  float* ws = (float*)d_ws;
  size_t off = 0;
  auto alloc = [&](size_t n) {
    float* p = ws + off;
    off += (n + 127) & ~(size_t)127;
    return p;
  };
  int* row_beg = (int*)alloc(N);
  int* row_end = (int*)alloc(N);
  int* esrc = (int*)alloc((size_t)NB * cap);
  // records (NB*cap uints) region, later reused as xs (bf16 N x 64 = N*32 uints)
  size_t recsz = ((size_t)NB * cap > (size_t)N * 32 ? (size_t)NB * cap : (size_t)N * 32);
  float* recbuf = alloc(recsz);
  float* dis = alloc(N);
  float* y1b = alloc((size_t)N * 32);   // bf16 N x 64
  float* h1b = alloc((size_t)N * 64);   // bf16 N x 128
  float* h2b = alloc((size_t)N * 64);   // bf16 N x 128
  float* zb_ = alloc((size_t)N * 64);   // bf16 N x 128
  float* w1tb = alloc(128 * 64 / 2);    // bf16 128x64 (col-major Wt)
  float* w2tb = alloc(128 * 128 / 2);   // bf16 128x128
  int* gcursor = (int*)alloc(NBMAX);
  int* gstart = (int*)alloc(NGRAPH + 1);
  float* zero0 = ws + off;              // zeroed region start
  float* gsum1 = alloc(NGRAPH * HID);
  float* gsq1 = alloc(NGRAPH * HID);
  float* gsum2 = alloc(NGRAPH * HID);
  float* gsq2 = alloc(NGRAPH * HID);
  float* pooled = alloc(NGRAPH * HID);
  size_t zero_bytes = (size_t)((ws + off) - zero0) * sizeof(float);
  float* cnt = alloc(NGRAPH);
  float* mean1 = alloc(NGRAPH * HID);
  float* inv1 = alloc(NGRAPH * HID);
  float* mean2 = alloc(NGRAPH * HID);
  float* inv2 = alloc(NGRAPH * HID);

  uint* records = (uint*)recbuf;
  ushort* xs = (ushort*)recbuf;  // alias: records dead after build_csr
  ushort* y1 = (ushort*)y1b;
  ushort* h1 = (ushort*)h1b;
  ushort* h2s = (ushort*)h2b;
  ushort* z = (ushort*)zb_;
  ushort* w1t = (ushort*)w1tb;
  ushort* w2t = (ushort*)w2tb;

  const int nblkN = (N + 255) / 256;
  const int nblkE4k = (E + 4095) / 4096;

  hipMemsetAsync(zero0, 0, zero_bytes, stream);

  // weight transposes (independent of everything else)
  wt_bf16<64><<<(128 * 64 + 255) / 256, 256, 0, stream>>>(W1, w1t);
  wt_bf16<128><<<(128 * 128 + 255) / 256, 256, 0, stream>>>(W2, w2t);

  // graph segments + padded CSR build
  graph_starts<<<nblkN, 256, 0, stream>>>(batch, gstart, N);
  cnt_from_starts<<<1, 64, 0, stream>>>(gstart, cnt);
  init_cursor<<<(NB + 255) / 256, 256, 0, stream>>>(gcursor, NB, cap);
  bin_edges<<<nblkE4k, 256, 0, stream>>>(srcp, dstp, gcursor, records, E, NB, cap);
  build_csr<<<NB, 256, 0, stream>>>(records, gcursor, row_beg, row_end, dis, esrc, N, cap);

  const int aggBlocks = (N + 3) / 4;     // one wave per node
  const int gemmBlocks = (N + 63) / 64;  // 64 rows per block

  // ---- layer 1: xs = bf16(x*dis); y1 = A-hat x (bf16); h1 = y1 @ W1 + b1 (bf16) ----
  xscale_bf16<<<(N * 16 + 255) / 256, 256, 0, stream>>>(x, dis, xs, N * 16);
  aggregate64<<<aggBlocks, 256, 0, stream>>>(xs, row_beg, row_end, esrc, dis, y1, N);
  gemm_mfma<64, false, false, true><<<gemmBlocks, 256, 0, stream>>>(
      y1, w1t, b1, nullptr, nullptr, nullptr, nullptr, h1, N);
  stats_pass<<<(N + 63) / 64, 256, 0, stream>>>(h1, batch, gsum1, gsq1, N);
  finalize_stats<<<(NGRAPH * HID + 255) / 256, 256, 0, stream>>>(gsum1, gsq1, cnt, mean1, inv1);

  // ---- layer 2: h2s = bf16(relu(norm(h1)) @ W2 * dis); z = A-hat h2 + b2 (bf16) ----
  gemm_mfma<128, true, true, false><<<gemmBlocks, 256, 0, stream>>>(
      h1, w2t, nullptr, batch, mean1, inv1, dis, h2s, N);
  aggregate128<<<aggBlocks, 256, 0, stream>>>(h2s, row_beg, row_end, esrc, dis, b2, z, N);
  stats_pass<<<(N + 63) / 64, 256, 0, stream>>>(z, batch, gsum2, gsq2, N);
  finalize_stats<<<(NGRAPH * HID + 255) / 256, 256, 0, stream>>>(gsum2, gsq2, cnt, mean2, inv2);
  norm_relu_pool<<<(N + 63) / 64, 256, 0, stream>>>(z, batch, mean2, inv2, pooled, N);

  // ---- head ----
  final_head<<<1, 256, 0, stream>>>(pooled, cnt, gamma, beta, fcW, fcb, out);
}

// Round 13
// 302.650 us; speedup vs baseline: 1.7772x; 1.0164x over previous
//
#include <hip/hip_runtime.h>
#include <hip/hip_bf16.h>

// GCN classifier: N=100000, E=1.6M, IN=64, HID=128, 64 graphs, 2 classes.
// Round 13: 2-nodes-per-wave gathers (one load instr = two rows; 16 rows in
// flight/wave), relative bucket cursors (init_cursor gone), cnt from gstart
// (cnt_from_starts gone), merged weight transpose, uint-vectorized stats/pool.

#define HID 128
#define NGRAPH 64
#define EPSN 1e-5f
#define BSHIFT 8            // 256 nodes per bucket
#define NBMAX 512

typedef unsigned int uint;
typedef unsigned short ushort;
typedef __attribute__((ext_vector_type(8))) short short8;   // 8 bf16 (4 VGPRs)
typedef __attribute__((ext_vector_type(4))) float f32x4;    // MFMA accumulator

static __device__ __forceinline__ ushort f2bf(float f) {  // round-nearest-even
  uint x = __float_as_uint(f);
  return (ushort)((x + 0x7FFFu + ((x >> 16) & 1u)) >> 16);
}
static __device__ __forceinline__ float bf_lo(uint u) { return __uint_as_float(u << 16); }
static __device__ __forceinline__ float bf_hi(uint u) {
  return __uint_as_float(u & 0xFFFF0000u);
}

// ---------------- per-graph segment boundaries (batch sorted) ----------------
__global__ __launch_bounds__(256) void graph_starts(const int* __restrict__ batch,
                                                    int* __restrict__ gstart, int N) {
  int i = blockIdx.x * 256 + threadIdx.x;
  if (i >= N) return;
  int g = batch[i];
  if (i == 0) {
    for (int q = 0; q <= g; ++q) gstart[q] = 0;
  } else {
    int gp = batch[i - 1];
    if (g != gp)
      for (int q = gp + 1; q <= g; ++q) gstart[q] = i;
  }
  if (i == N - 1)
    for (int q = g + 1; q <= NGRAPH; ++q) gstart[q] = N;
}

// ---------------- padded-bucket counting sort: CSR build ----------------
// packed record: (src << 8) | (dst & 255)   [src < 2^24]
// gcursor is RELATIVE (zeroed by memset); absolute base = bucket*cap.
__global__ __launch_bounds__(256) void bin_edges(const int* __restrict__ src,
                                                 const int* __restrict__ dst,
                                                 int* __restrict__ gcursor,
                                                 uint* __restrict__ records, int E, int NB,
                                                 int cap) {
  __shared__ int h[NBMAX];
  __shared__ int base[NBMAX];
  for (int i = threadIdx.x; i < NB; i += 256) h[i] = 0;
  __syncthreads();
  int e0 = blockIdx.x * 4096;
  int d[16], s[16];
#pragma unroll
  for (int k = 0; k < 16; ++k) {
    int e = e0 + k * 256 + threadIdx.x;
    if (e < E) {
      d[k] = dst[e];
      s[k] = src[e];
      atomicAdd(&h[d[k] >> BSHIFT], 1);
    }
  }
  __syncthreads();
  for (int i = threadIdx.x; i < NB; i += 256) {
    int c = h[i];
    if (c) base[i] = i * cap + atomicAdd(&gcursor[i], c);
  }
  __syncthreads();
  for (int i = threadIdx.x; i < NB; i += 256) h[i] = 0;  // reuse as local cursor
  __syncthreads();
#pragma unroll
  for (int k = 0; k < 16; ++k) {
    int e = e0 + k * 256 + threadIdx.x;
    if (e < E) {
      int b = d[k] >> BSHIFT;
      int lp = atomicAdd(&h[b], 1);
      records[base[b] + lp] = ((uint)s[k] << 8) | (uint)(d[k] & 255);
    }
  }
}

// one block per bucket: local count/scan -> row_beg/row_end, dis, esrc (padded).
__global__ __launch_bounds__(256) void build_csr(const uint* __restrict__ records,
                                                 const int* __restrict__ gcursor,
                                                 int* __restrict__ row_beg,
                                                 int* __restrict__ row_end,
                                                 float* __restrict__ dis,
                                                 int* __restrict__ esrc, int N, int cap) {
  const int b = blockIdx.x;
  const int node0 = b << BSHIFT;
  const int nn = min(256, N - node0);
  const int beg = b * cap;
  const int cnt = gcursor[b];  // relative count
  const int t = threadIdx.x;
  __shared__ int lc[256], sc[256], lcur[256];
  lc[t] = 0;
  __syncthreads();
  for (int i = t; i < cnt; i += 256) atomicAdd(&lc[records[beg + i] & 255u], 1);
  __syncthreads();
  int myc = lc[t];
  sc[t] = myc;
  __syncthreads();
  for (int off = 1; off < 256; off <<= 1) {
    int add = (t >= off) ? sc[t - off] : 0;
    __syncthreads();
    sc[t] += add;
    __syncthreads();
  }
  int excl = sc[t] - myc;
  if (t < nn) {
    row_beg[node0 + t] = beg + excl;
    row_end[node0 + t] = beg + excl + myc;
    dis[node0 + t] = rsqrtf((float)myc + 1.0f);  // +1 self-loop
  }
  lcur[t] = excl;
  __syncthreads();
  for (int i = t; i < cnt; i += 256) {
    uint r = records[beg + i];
    int p = atomicAdd(&lcur[r & 255u], 1);
    esrc[beg + p] = (int)(r >> 8);
  }
}

// ---------------- xs = bf16(x * dis[row]) ----------------
__global__ __launch_bounds__(256) void xscale_bf16(const float* __restrict__ X,
                                                   const float* __restrict__ dis,
                                                   ushort* __restrict__ XS, int n4) {
  int i4 = blockIdx.x * 256 + threadIdx.x;  // unit = float4
  if (i4 >= n4) return;
  int n = i4 >> 4;  // 16 float4 per 64-ch row
  float dn = dis[n];
  float4 v = ((const float4*)X)[i4];
  ushort4 u;
  u.x = f2bf(v.x * dn);
  u.y = f2bf(v.y * dn);
  u.z = f2bf(v.z * dn);
  u.w = f2bf(v.w * dn);
  ((ushort4*)XS)[i4] = u;
}

// ---------------- both weight transposes: W (Kx128 f32) -> Wt (128xK bf16) ----------------
__global__ __launch_bounds__(256) void wt_both(const float* __restrict__ W1,
                                               const float* __restrict__ W2,
                                               ushort* __restrict__ w1t,
                                               ushort* __restrict__ w2t) {
  int i = blockIdx.x * 256 + threadIdx.x;
  if (i < 128 * 64) {
    int c = i / 64, k = i - c * 64;
    w1t[i] = f2bf(W1[(size_t)k * HID + c]);
  } else {
    int i2 = i - 128 * 64;
    if (i2 < 128 * 128) {
      int c = i2 / 128, k = i2 - c * 128;
      w2t[i2] = f2bf(W2[(size_t)k * HID + c]);
    }
  }
}

// ---------------- aggregate 64-ch bf16, 2 nodes/wave, 8-edge unroll ----------------
// half-wave per node: lane j=l&31 holds uint (2 ch); one load instr = 2 rows.
__global__ __launch_bounds__(256) void aggregate64(const ushort* __restrict__ XS,
                                                   const int* __restrict__ row_beg,
                                                   const int* __restrict__ row_end,
                                                   const int* __restrict__ esrc,
                                                   const float* __restrict__ dis,
                                                   ushort* __restrict__ out, int N) {
  int wave = (int)((blockIdx.x * 256 + threadIdx.x) >> 6);
  const int l = threadIdx.x & 63;
  const int n = wave * 2 + (l >> 5);
  if (n >= N) return;
  const int j = l & 31;  // uint slot: channels 2j, 2j+1
  const float dn = dis[n];
  const int beg = row_beg[n];
  const int len = row_end[n] - beg;
  const uint* Xj = (const uint*)XS + j;  // row stride 32 uints
  float a0 = 0.f, a1 = 0.f, b0 = 0.f, b1 = 0.f;
  int i = 0;
  for (; i + 7 < len; i += 8) {
    int s0 = esrc[beg + i], s1 = esrc[beg + i + 1];
    int s2 = esrc[beg + i + 2], s3 = esrc[beg + i + 3];
    int s4 = esrc[beg + i + 4], s5 = esrc[beg + i + 5];
    int s6 = esrc[beg + i + 6], s7 = esrc[beg + i + 7];
    uint u0 = Xj[(size_t)s0 * 32];
    uint u1 = Xj[(size_t)s1 * 32];
    uint u2 = Xj[(size_t)s2 * 32];
    uint u3 = Xj[(size_t)s3 * 32];
    uint u4 = Xj[(size_t)s4 * 32];
    uint u5 = Xj[(size_t)s5 * 32];
    uint u6 = Xj[(size_t)s6 * 32];
    uint u7 = Xj[(size_t)s7 * 32];
    a0 += bf_lo(u0) + bf_lo(u1) + bf_lo(u2) + bf_lo(u3);
    a1 += bf_hi(u0) + bf_hi(u1) + bf_hi(u2) + bf_hi(u3);
    b0 += bf_lo(u4) + bf_lo(u5) + bf_lo(u6) + bf_lo(u7);
    b1 += bf_hi(u4) + bf_hi(u5) + bf_hi(u6) + bf_hi(u7);
  }
  for (; i < len; ++i) {
    uint u = Xj[(size_t)esrc[beg + i] * 32];
    a0 += bf_lo(u);
    a1 += bf_hi(u);
  }
  uint us = Xj[(size_t)n * 32];  // self (prescaled)
  a0 += b0 + bf_lo(us);
  a1 += b1 + bf_hi(us);
  ((uint*)out)[(size_t)n * 32 + j] = (uint)f2bf(a0 * dn) | ((uint)f2bf(a1 * dn) << 16);
}

// ---------------- aggregate 128-ch bf16 + bias, 2 nodes/wave, 8-edge unroll ----------------
// half-wave per node: lane j=l&31 holds uint2 (4 ch); one load instr = 2 rows.
__global__ __launch_bounds__(256) void aggregate128(const ushort* __restrict__ H,
                                                    const int* __restrict__ row_beg,
                                                    const int* __restrict__ row_end,
                                                    const int* __restrict__ esrc,
                                                    const float* __restrict__ dis,
                                                    const float* __restrict__ bias,
                                                    ushort* __restrict__ outz, int N) {
  int wave = (int)((blockIdx.x * 256 + threadIdx.x) >> 6);
  const int l = threadIdx.x & 63;
  const int n = wave * 2 + (l >> 5);
  if (n >= N) return;
  const int j = l & 31;  // uint2 slot: channels 4j..4j+3
  const float dn = dis[n];
  const int beg = row_beg[n];
  const int len = row_end[n] - beg;
  const uint2* Hj = (const uint2*)H + j;  // row stride 32 uint2
  float a0 = 0.f, a1 = 0.f, a2 = 0.f, a3 = 0.f;
  float b0 = 0.f, b1 = 0.f, b2 = 0.f, b3 = 0.f;
  int i = 0;
  for (; i + 7 < len; i += 8) {
    int s0 = esrc[beg + i], s1 = esrc[beg + i + 1];
    int s2 = esrc[beg + i + 2], s3 = esrc[beg + i + 3];
    int s4 = esrc[beg + i + 4], s5 = esrc[beg + i + 5];
    int s6 = esrc[beg + i + 6], s7 = esrc[beg + i + 7];
    uint2 u0 = Hj[(size_t)s0 * 32];
    uint2 u1 = Hj[(size_t)s1 * 32];
    uint2 u2 = Hj[(size_t)s2 * 32];
    uint2 u3 = Hj[(size_t)s3 * 32];
    uint2 u4 = Hj[(size_t)s4 * 32];
    uint2 u5 = Hj[(size_t)s5 * 32];
    uint2 u6 = Hj[(size_t)s6 * 32];
    uint2 u7 = Hj[(size_t)s7 * 32];
    a0 += bf_lo(u0.x) + bf_lo(u1.x) + bf_lo(u2.x) + bf_lo(u3.x);
    a1 += bf_hi(u0.x) + bf_hi(u1.x) + bf_hi(u2.x) + bf_hi(u3.x);
    a2 += bf_lo(u0.y) + bf_lo(u1.y) + bf_lo(u2.y) + bf_lo(u3.y);
    a3 += bf_hi(u0.y) + bf_hi(u1.y) + bf_hi(u2.y) + bf_hi(u3.y);
    b0 += bf_lo(u4.x) + bf_lo(u5.x) + bf_lo(u6.x) + bf_lo(u7.x);
    b1 += bf_hi(u4.x) + bf_hi(u5.x) + bf_hi(u6.x) + bf_hi(u7.x);
    b2 += bf_lo(u4.y) + bf_lo(u5.y) + bf_lo(u6.y) + bf_lo(u7.y);
    b3 += bf_hi(u4.y) + bf_hi(u5.y) + bf_hi(u6.y) + bf_hi(u7.y);
  }
  for (; i < len; ++i) {
    uint2 u = Hj[(size_t)esrc[beg + i] * 32];
    a0 += bf_lo(u.x);
    a1 += bf_hi(u.x);
    a2 += bf_lo(u.y);
    a3 += bf_hi(u.y);
  }
  uint2 us = Hj[(size_t)n * 32];  // self (prescaled)
  a0 += b0 + bf_lo(us.x);
  a1 += b1 + bf_hi(us.x);
  a2 += b2 + bf_lo(us.y);
  a3 += b3 + bf_hi(us.y);
  float4 bv = ((const float4*)bias)[j];
  uint2 o;
  o.x = (uint)f2bf(a0 * dn + bv.x) | ((uint)f2bf(a1 * dn + bv.y) << 16);
  o.y = (uint)f2bf(a2 * dn + bv.z) | ((uint)f2bf(a3 * dn + bv.w) << 16);
  ((uint2*)outz)[(size_t)n * 32 + j] = o;
}

// ---------------- MFMA GEMM: Y[N][128] = bf16X[N][K] @ W[K][128] -> bf16 ----------------
template <int K, bool FUSE_NORM, bool DIS_SCALE, bool HAS_BIAS>
__global__ __launch_bounds__(256) void gemm_mfma(const ushort* __restrict__ X,
                                                 const ushort* __restrict__ Wt,
                                                 const float* __restrict__ bias,
                                                 const int* __restrict__ batch,
                                                 const float* __restrict__ mean,
                                                 const float* __restrict__ inv,
                                                 const float* __restrict__ disv,
                                                 ushort* __restrict__ Y, int N) {
  const int t = threadIdx.x;
  const int w = t >> 6;
  const int l = t & 63;
  const int lr = l & 15;   // A row / B-D col within tile
  const int lk = l >> 4;   // k-group 0..3 (also D row group)
  const int row0 = blockIdx.x * 64 + w * 16;
  const int arow = min(row0 + lr, N - 1);  // clamp: OOB rows produce discarded C rows
  int g = 0;
  if (FUSE_NORM) g = batch[arow];
  f32x4 acc[8];
#pragma unroll
  for (int i = 0; i < 8; ++i) acc[i] = (f32x4){0.f, 0.f, 0.f, 0.f};
#pragma unroll
  for (int k0 = 0; k0 < K; k0 += 32) {
    const int kbase = k0 + lk * 8;
    short8 a = *(const short8*)(X + (size_t)arow * K + kbase);
    if (FUSE_NORM) {
      const float* mp = mean + g * HID + kbase;
      const float* ip = inv + g * HID + kbase;
      short8 an;
#pragma unroll
      for (int j = 0; j < 8; ++j) {
        float f = __uint_as_float((uint)(ushort)a[j] << 16);
        f = fmaxf((f - mp[j]) * ip[j], 0.f);
        an[j] = (short)f2bf(f);
      }
      a = an;
    }
#pragma unroll
    for (int nf = 0; nf < 8; ++nf) {
      short8 b = *(const short8*)(Wt + (size_t)(nf * 16 + lr) * K + kbase);
      acc[nf] = __builtin_amdgcn_mfma_f32_16x16x32_bf16(a, b, acc[nf], 0, 0, 0);
    }
  }
#pragma unroll
  for (int r = 0; r < 4; ++r) {
    int grow = row0 + lk * 4 + r;
    if (grow < N) {
      float ds = DIS_SCALE ? disv[grow] : 1.f;
#pragma unroll
      for (int nf = 0; nf < 8; ++nf) {
        int col = nf * 16 + lr;
        float v = acc[nf][r];
        if (HAS_BIAS) v += bias[col];
        v *= ds;
        Y[(size_t)grow * HID + col] = f2bf(v);
      }
    }
  }
}

// ---------------- per-graph sum/sumsq (bf16 input, uint loads) ----------------
__global__ __launch_bounds__(256) void stats_pass(const ushort* __restrict__ G,
                                                  const int* __restrict__ batch,
                                                  float* __restrict__ gsum,
                                                  float* __restrict__ gsq, int N) {
  const int c2 = threadIdx.x & 63;   // uint slot: ch 2c2, 2c2+1
  const int sub = threadIdx.x >> 6;  // 0..3
  const int n0 = blockIdx.x * 64 + sub * 16;
  const int n1 = min(n0 + 16, N);
  const uint* Gj = (const uint*)G + c2;  // row stride 64 uints
  float s0 = 0.f, s1 = 0.f, q0 = 0.f, q1 = 0.f;
  int cur = -1;
  for (int n = n0; n < n1; ++n) {
    int g = batch[n];
    if (g != cur) {
      if (cur >= 0) {
        atomicAdd(&gsum[cur * HID + 2 * c2], s0);
        atomicAdd(&gsum[cur * HID + 2 * c2 + 1], s1);
        atomicAdd(&gsq[cur * HID + 2 * c2], q0);
        atomicAdd(&gsq[cur * HID + 2 * c2 + 1], q1);
      }
      cur = g;
      s0 = s1 = q0 = q1 = 0.f;
    }
    uint u = Gj[(size_t)n * 64];
    float v0 = bf_lo(u), v1 = bf_hi(u);
    s0 += v0;
    s1 += v1;
    q0 += v0 * v0;
    q1 += v1 * v1;
  }
  if (cur >= 0) {
    atomicAdd(&gsum[cur * HID + 2 * c2], s0);
    atomicAdd(&gsum[cur * HID + 2 * c2 + 1], s1);
    atomicAdd(&gsq[cur * HID + 2 * c2], q0);
    atomicAdd(&gsq[cur * HID + 2 * c2 + 1], q1);
  }
}

__global__ __launch_bounds__(256) void finalize_stats(const float* __restrict__ gsum,
                                                      const float* __restrict__ gsq,
                                                      const int* __restrict__ gstart,
                                                      float* __restrict__ mean,
                                                      float* __restrict__ inv) {
  int i = blockIdx.x * 256 + threadIdx.x;
  if (i >= NGRAPH * HID) return;
  int g = i >> 7;
  float c = fmaxf((float)(gstart[g + 1] - gstart[g]), 1.f);
  float m = gsum[i] / c;
  float v = gsq[i] / c - m * m;
  mean[i] = m;
  inv[i] = rsqrtf(v + EPSN);
}

// ---------------- norm+relu+pool (bf16 input, uint loads) ----------------
__global__ __launch_bounds__(256) void norm_relu_pool(const ushort* __restrict__ G,
                                                      const int* __restrict__ batch,
                                                      const float* __restrict__ mean,
                                                      const float* __restrict__ inv,
                                                      float* __restrict__ pooled, int N) {
  const int c2 = threadIdx.x & 63;
  const int sub = threadIdx.x >> 6;
  const int n0 = blockIdx.x * 64 + sub * 16;
  const int n1 = min(n0 + 16, N);
  const uint* Gj = (const uint*)G + c2;
  float p0 = 0.f, p1 = 0.f;
  int cur = -1;
  float2 mv = {0.f, 0.f}, iv = {0.f, 0.f};
  for (int n = n0; n < n1; ++n) {
    int g = batch[n];
    if (g != cur) {
      if (cur >= 0) {
        atomicAdd(&pooled[cur * HID + 2 * c2], p0);
        atomicAdd(&pooled[cur * HID + 2 * c2 + 1], p1);
      }
      cur = g;
      p0 = p1 = 0.f;
      mv = ((const float2*)mean)[g * 64 + c2];
      iv = ((const float2*)inv)[g * 64 + c2];
    }
    uint u = Gj[(size_t)n * 64];
    p0 += fmaxf((bf_lo(u) - mv.x) * iv.x, 0.f);
    p1 += fmaxf((bf_hi(u) - mv.y) * iv.y, 0.f);
  }
  if (cur >= 0) {
    atomicAdd(&pooled[cur * HID + 2 * c2], p0);
    atomicAdd(&pooled[cur * HID + 2 * c2 + 1], p1);
  }
}

// ---------------- final head ----------------
__global__ __launch_bounds__(256) void final_head(const float* __restrict__ pooled_sum,
                                                  const int* __restrict__ gstart,
                                                  const float* __restrict__ gamma,
                                                  const float* __restrict__ beta,
                                                  const float* __restrict__ fcW,
                                                  const float* __restrict__ fcb,
                                                  float* __restrict__ out) {
  __shared__ float P[NGRAPH][HID];
  __shared__ float zs[HID], zb[HID];
  int t = threadIdx.x;
  for (int i = t; i < NGRAPH * HID; i += 256) {
    int g = i >> 7;
    float c = fmaxf((float)(gstart[g + 1] - gstart[g]), 1.f);
    P[g][i & 127] = pooled_sum[i] / c;
  }
  __syncthreads();
  if (t < HID) {
    float m = 0.f;
    for (int g = 0; g < NGRAPH; ++g) m += P[g][t];
    m *= (1.f / NGRAPH);
    float v = 0.f;
    for (int g = 0; g < NGRAPH; ++g) {
      float d = P[g][t] - m;
      v += d * d;
    }
    v *= (1.f / NGRAPH);
    float sc = rsqrtf(v + EPSN) * gamma[t];
    zs[t] = sc;
    zb[t] = beta[t] - m * sc;
  }
  __syncthreads();
  if (t < NGRAPH * 2) {
    int g = t >> 1, k = t & 1;
    float acc = fcb[k];
    for (int c = 0; c < HID; ++c) {
      float z = P[g][c] * zs[c] + zb[c];
      acc += z * fcW[c * 2 + k];
    }
    out[t] = acc;
  }
}

extern "C" void kernel_launch(void* const* d_in, const int* in_sizes, int n_in,
                              void* d_out, int out_size, void* d_ws, size_t ws_size,
                              hipStream_t stream) {
  const float* x = (const float*)d_in[0];
  const int* ei = (const int*)d_in[1];     // int32
  const int* batch = (const int*)d_in[2];  // int32 (sorted)
  const float* W1 = (const float*)d_in[3];
  const float* b1 = (const float*)d_in[4];
  const float* W2 = (const float*)d_in[5];
  const float* b2 = (const float*)d_in[6];
  const float* gamma = (const float*)d_in[7];
  const float* beta = (const float*)d_in[8];
  const float* fcW = (const float*)d_in[9];
  const float* fcb = (const float*)d_in[10];
  float* out = (float*)d_out;

  const int N = in_sizes[2];
  const int E = in_sizes[1] / 2;
  const int* srcp = ei;
  const int* dstp = ei + E;
  const int NB = (N + 255) >> BSHIFT;       // buckets (<=512 for N<=131072)
  const int cap = 2 * (E / NB) + 256;       // per-bucket capacity (~64 sigma margin)

  // workspace layout (floats)
  float* ws = (float*)d_ws;
  size_t off = 0;
  auto alloc = [&](size_t n) {
    float* p = ws + off;
    off += (n + 127) & ~(size_t)127;
    return p;
  };
  int* row_beg = (int*)alloc(N);
  int* row_end = (int*)alloc(N);
  int* esrc = (int*)alloc((size_t)NB * cap);
  // records (NB*cap uints) region, later reused as xs (bf16 N x 64 = N*32 uints)
  size_t recsz = ((size_t)NB * cap > (size_t)N * 32 ? (size_t)NB * cap : (size_t)N * 32);
  float* recbuf = alloc(recsz);
  float* dis = alloc(N);
  float* y1b = alloc((size_t)N * 32);   // bf16 N x 64
  float* h1b = alloc((size_t)N * 64);   // bf16 N x 128
  float* h2b = alloc((size_t)N * 64);   // bf16 N x 128
  float* zb_ = alloc((size_t)N * 64);   // bf16 N x 128
  float* w1tb = alloc(128 * 64 / 2);    // bf16 128x64 (col-major Wt)
  float* w2tb = alloc(128 * 128 / 2);   // bf16 128x128
  int* gstart = (int*)alloc(NGRAPH + 1);
  float* zero0 = ws + off;              // zeroed region start
  int* gcursor = (int*)alloc(NBMAX);    // relative cursors (must be zeroed)
  float* gsum1 = alloc(NGRAPH * HID);
  float* gsq1 = alloc(NGRAPH * HID);
  float* gsum2 = alloc(NGRAPH * HID);
  float* gsq2 = alloc(NGRAPH * HID);
  float* pooled = alloc(NGRAPH * HID);
  size_t zero_bytes = (size_t)((ws + off) - zero0) * sizeof(float);
  float* mean1 = alloc(NGRAPH * HID);
  float* inv1 = alloc(NGRAPH * HID);
  float* mean2 = alloc(NGRAPH * HID);
  float* inv2 = alloc(NGRAPH * HID);

  uint* records = (uint*)recbuf;
  ushort* xs = (ushort*)recbuf;  // alias: records dead after build_csr
  ushort* y1 = (ushort*)y1b;
  ushort* h1 = (ushort*)h1b;
  ushort* h2s = (ushort*)h2b;
  ushort* z = (ushort*)zb_;
  ushort* w1t = (ushort*)w1tb;
  ushort* w2t = (ushort*)w2tb;

  const int nblkN = (N + 255) / 256;
  const int nblkE4k = (E + 4095) / 4096;

  hipMemsetAsync(zero0, 0, zero_bytes, stream);

  // weight transposes + graph segments + padded CSR build
  wt_both<<<(128 * 64 + 128 * 128 + 255) / 256, 256, 0, stream>>>(W1, W2, w1t, w2t);
  graph_starts<<<nblkN, 256, 0, stream>>>(batch, gstart, N);
  bin_edges<<<nblkE4k, 256, 0, stream>>>(srcp, dstp, gcursor, records, E, NB, cap);
  build_csr<<<NB, 256, 0, stream>>>(records, gcursor, row_beg, row_end, dis, esrc, N, cap);

  const int aggBlocks = ((N + 1) / 2 + 3) / 4;  // 2 nodes per wave, 4 waves/block
  const int gemmBlocks = (N + 63) / 64;         // 64 rows per block
  const int nrmBlocks = (N + 63) / 64;          // stats/pool: 64 nodes per block

  // ---- layer 1: xs = bf16(x*dis); y1 = A-hat x (bf16); h1 = y1 @ W1 + b1 (bf16) ----
  xscale_bf16<<<(N * 16 + 255) / 256, 256, 0, stream>>>(x, dis, xs, N * 16);
  aggregate64<<<aggBlocks, 256, 0, stream>>>(xs, row_beg, row_end, esrc, dis, y1, N);
  gemm_mfma<64, false, false, true><<<gemmBlocks, 256, 0, stream>>>(
      y1, w1t, b1, nullptr, nullptr, nullptr, nullptr, h1, N);
  stats_pass<<<nrmBlocks, 256, 0, stream>>>(h1, batch, gsum1, gsq1, N);
  finalize_stats<<<(NGRAPH * HID + 255) / 256, 256, 0, stream>>>(gsum1, gsq1, gstart, mean1, inv1);

  // ---- layer 2: h2s = bf16(relu(norm(h1)) @ W2 * dis); z = A-hat h2 + b2 (bf16) ----
  gemm_mfma<128, true, true, false><<<gemmBlocks, 256, 0, stream>>>(
      h1, w2t, nullptr, batch, mean1, inv1, dis, h2s, N);
  aggregate128<<<aggBlocks, 256, 0, stream>>>(h2s, row_beg, row_end, esrc, dis, b2, z, N);
  stats_pass<<<nrmBlocks, 256, 0, stream>>>(z, batch, gsum2, gsq2, N);
  finalize_stats<<<(NGRAPH * HID + 255) / 256, 256, 0, stream>>>(gsum2, gsq2, gstart, mean2, inv2);
  norm_relu_pool<<<nrmBlocks, 256, 0, stream>>>(z, batch, mean2, inv2, pooled, N);

  // ---- head ----
  final_head<<<1, 256, 0, stream>>>(pooled, gstart, gamma, beta, fcW, fcb, out);
}